// Round 8
// baseline (812.442 us; speedup 1.0000x reference)
//
#include <hip/hip_runtime.h>
#include <hip/hip_bf16.h>
#include <float.h>
#include <math.h>

#define NB 8
#define CCH 384
#define NHEAD 6
#define DHEAD 64
#define AAD 48
#define MSEG 1024
#define NSUP 6
#define NTOK 8200
#define NFEAT 8192
#define SEG2 1536
#define SEQ 1025
#define SEQP 1088

typedef __hip_bfloat16 bf16;
typedef __attribute__((ext_vector_type(8))) short short8;
typedef __attribute__((ext_vector_type(4))) float floatx4;

// feat row n (0..8191) -> row index in (B,1025,C) token array, skipping CLS
static __device__ __forceinline__ long long tokrow(int n) {
  return (long long)n + (n >> 10) + 1;
}

template<int NT>
static __device__ __forceinline__ float block_reduce_sum(float v, float* s) {
  #pragma unroll
  for (int off = 32; off > 0; off >>= 1) v += __shfl_down(v, off, 64);
  int lane = threadIdx.x & 63, wid = threadIdx.x >> 6;
  if (lane == 0) s[wid] = v;
  __syncthreads();
  if (threadIdx.x == 0) {
    float t = s[0];
    #pragma unroll
    for (int w = 1; w < NT / 64; w++) t += s[w];
    s[0] = t;
  }
  __syncthreads();
  float r = s[0];
  __syncthreads();
  return r;
}

// ---------------------------------------------------------------------------
// MFMA bf16 GEMM, latency-oriented:  C[m,n] = sum_k A[m,k]*Bt[n,k] (Bt: N x K)
// Wave tile 64x32 (acc = 32 VGPR), block = WM x WN waves of 256 threads,
// block tile (WM*64) x (WN*32). BK=64, single LDS buffer (24 KB at <2,2>).
// REGISTER-PREFETCH pipeline: tile t+1 global->regs issued before computing
// tile t from LDS; regs->LDS write after barrier absorbs residual latency
// per-wave (no block-wide naked vmcnt(0)).
// LDS layout: [row][8 granules 16B], granule slot g holds global granule
// g^(row&7) -> conflict-free ds_read_b128 (verified 0 conflicts in R4).
// ---------------------------------------------------------------------------
template<int WM, int WN>
__global__ __launch_bounds__(256) void mgemm_kernel(
    const bf16* __restrict__ A, int lda, long long sAh,
    const bf16* __restrict__ B, int ldb, long long sBh,
    float* __restrict__ outF, int ldcF, long long sCFh,
    bf16* __restrict__ outB, int ldcB, long long sCBh,
    int M, int N, int K,
    const float* __restrict__ bias, long long sBias, int act, float scale,
    const float* __restrict__ rowmask, long long sMask,
    const float* __restrict__ res1, int ldr1, int res1skip,
    const float* __restrict__ res2, int ldr2)
{
  constexpr int BM = WM * 64, BN = WN * 32;
  __shared__ uint4 Asg[BM * 8];
  __shared__ uint4 Bsg[BN * 8];
  const int z = blockIdx.z;
  const bf16* Ap = A + (long long)z * sAh;
  const bf16* Bp = B + (long long)z * sBh;
  const int tid = threadIdx.x;
  const int m0 = blockIdx.y * BM, n0 = blockIdx.x * BN;
  const int lane = tid & 63, wid = tid >> 6;
  const int wm = (wid % WM) * 64, wn = (wid / WM) * 32;
  const int q = lane >> 4, ln = lane & 15;
  const uint4 zero4 = make_uint4(0, 0, 0, 0);

  uint4 areg[2 * WM], breg[WN];

  auto loadregs = [&](int k0) {
    #pragma unroll
    for (int p = 0; p < 2 * WM; p++) {
      int idx = p * 256 + tid;
      int row = idx >> 3, g = idx & 7;
      int gs = g ^ (row & 7);
      int gm = m0 + row, gk = k0 + gs * 8;
      areg[p] = (gm < M && gk < K)
          ? *reinterpret_cast<const uint4*>(Ap + (long long)gm * lda + gk) : zero4;
    }
    #pragma unroll
    for (int p = 0; p < WN; p++) {
      int idx = p * 256 + tid;
      int row = idx >> 3, g = idx & 7;
      int gs = g ^ (row & 7);
      int gn = n0 + row, gk = k0 + gs * 8;
      breg[p] = (gn < N && gk < K)
          ? *reinterpret_cast<const uint4*>(Bp + (long long)gn * ldb + gk) : zero4;
    }
  };
  auto writeLDS = [&]() {
    #pragma unroll
    for (int p = 0; p < 2 * WM; p++) Asg[p * 256 + tid] = areg[p];
    #pragma unroll
    for (int p = 0; p < WN; p++) Bsg[p * 256 + tid] = breg[p];
  };

  floatx4 acc[4][2];
  #pragma unroll
  for (int i = 0; i < 4; i++)
    #pragma unroll
    for (int j = 0; j < 2; j++) acc[i][j] = (floatx4){0.f, 0.f, 0.f, 0.f};

  const int nk = (K + 63) >> 6;
  loadregs(0);
  writeLDS();
  __syncthreads();
  for (int t = 0; t < nk; t++) {
    if (t + 1 < nk) loadregs((t + 1) * 64);   // issue next tile's loads now
    #pragma unroll
    for (int ks = 0; ks < 2; ks++) {
      short8 af[4], bfr[2];
      #pragma unroll
      for (int i = 0; i < 4; i++) {
        int row = wm + i * 16 + ln;
        af[i] = *reinterpret_cast<const short8*>(
            &Asg[row * 8 + ((ks * 4 + q) ^ (ln & 7))]);
      }
      #pragma unroll
      for (int j = 0; j < 2; j++) {
        int row = wn + j * 16 + ln;
        bfr[j] = *reinterpret_cast<const short8*>(
            &Bsg[row * 8 + ((ks * 4 + q) ^ (ln & 7))]);
      }
      #pragma unroll
      for (int i = 0; i < 4; i++)
        #pragma unroll
        for (int j = 0; j < 2; j++)
          acc[i][j] = __builtin_amdgcn_mfma_f32_16x16x32_bf16(af[i], bfr[j], acc[i][j], 0, 0, 0);
    }
    if (t + 1 < nk) {
      __syncthreads();   // all waves done reading tile t
      writeLDS();        // implicit per-wave wait on loads via register use
      __syncthreads();   // tile t+1 visible
    }
  }

  const float* biasz = bias ? bias + z * sBias : nullptr;
  const float* rmz = rowmask ? rowmask + z * sMask : nullptr;
  float* cF = outF ? outF + (long long)z * sCFh : nullptr;
  bf16*  cB = outB ? outB + (long long)z * sCBh : nullptr;
  #pragma unroll
  for (int i = 0; i < 4; i++) {
    #pragma unroll
    for (int r = 0; r < 4; r++) {
      int gm = m0 + wm + i * 16 + q * 4 + r;
      if (gm >= M) continue;
      float rm = rmz ? rmz[gm] : 1.0f;
      long long r1off = 0;
      if (res1) r1off = (res1skip ? tokrow(gm) : (long long)gm) * ldr1;
      #pragma unroll
      for (int j = 0; j < 2; j++) {
        int gn = n0 + wn + j * 16 + ln;
        if (gn >= N) continue;
        float v = acc[i][j][r];
        if (biasz) v += biasz[gn];
        if (act) v = v / (1.0f + __expf(-1.702f * v));  // quick_gelu
        v *= scale * rm;
        if (res1) v += res1[r1off + gn];
        if (res2) v += res2[(long long)gm * ldr2 + gn];
        if (cF) cF[(long long)gm * ldcF + gn] = v;
        if (cB) cB[(long long)gm * ldcB + gn] = __float2bfloat16(v);
      }
    }
  }
}

// ---------------------------------------------------------------------------
// Unified weight-prep kernel (table over blockIdx.y):
//  y=0: w_in*ln1_g  y=1: w_fc*ln2_g  y=2..7: w_attn1[z]*gn3[z]
//  y=8: w_out  y=9: w_proj  y=10: wa1  y=11: wa2 padded to ld 64
// ---------------------------------------------------------------------------
__global__ void prep_kernel(
    const float* __restrict__ w_in, const float* __restrict__ ln1_g, bf16* __restrict__ w_in_b,
    const float* __restrict__ w_fc, const float* __restrict__ ln2_g, bf16* __restrict__ w_fc_b,
    const float* __restrict__ w_attn1, const float* __restrict__ gn3, bf16* __restrict__ wat_b,
    const float* __restrict__ w_out, bf16* __restrict__ w_out_b,
    const float* __restrict__ w_proj, bf16* __restrict__ w_pj_b,
    const float* __restrict__ wa1, bf16* __restrict__ wa1_b,
    const float* __restrict__ wa2, bf16* __restrict__ wa2_b)
{
  int y = blockIdx.y;
  int i = (blockIdx.x * 256 + threadIdx.x) * 4;
  if (y == 11) {
    if (i >= CCH * 64) return;
    int r = i >> 6, c = i & 63;
    #pragma unroll
    for (int e = 0; e < 4; e++)
      wa2_b[i + e] = __float2bfloat16((c + e) < AAD ? wa2[r * AAD + c + e] : 0.f);
    return;
  }
  const float* s; bf16* d; const float* g = nullptr; int n;
  if (y == 0)      { s = w_in;  d = w_in_b;  g = ln1_g; n = 3 * CCH * CCH; }
  else if (y == 1) { s = w_fc;  d = w_fc_b;  g = ln2_g; n = 4 * CCH * CCH; }
  else if (y <= 7) { int z = y - 2;
                     s = w_attn1 + (long long)z * CCH * CCH;
                     d = wat_b   + (long long)z * CCH * CCH;
                     g = gn3 + z * CCH; n = CCH * CCH; }
  else if (y == 8) { s = w_out;  d = w_out_b; n = CCH * CCH; }
  else if (y == 9) { s = w_proj; d = w_pj_b;  n = 4 * CCH * CCH; }
  else             { s = wa1;   d = wa1_b;   n = AAD * CCH; }
  if (i >= n) return;
  float4 v = *reinterpret_cast<const float4*>(s + i);
  if (g) {
    int k = i % CCH;
    v.x *= g[k]; v.y *= g[k + 1]; v.z *= g[k + 2]; v.w *= g[k + 3];
  }
  d[i]     = __float2bfloat16(v.x);
  d[i + 1] = __float2bfloat16(v.y);
  d[i + 2] = __float2bfloat16(v.z);
  d[i + 3] = __float2bfloat16(v.w);
}

// Unified bias-fold: out[n] = b[n] + sum_k beta[k] * W[n][k]; one wave/row.
__global__ __launch_bounds__(64) void fold_kernel(
    const float* __restrict__ w_in, const float* __restrict__ b_in,
    const float* __restrict__ ln1_b, float* __restrict__ b_in_f,
    const float* __restrict__ w_fc, const float* __restrict__ b_fc,
    const float* __restrict__ ln2_b, float* __restrict__ b_fc_f,
    const float* __restrict__ w_attn1, const float* __restrict__ b_attn1,
    const float* __restrict__ bn3, float* __restrict__ b_at_f)
{
  int y = blockIdx.y, n = blockIdx.x;
  const float* W; const float* b; const float* beta; float* o; int rows;
  if (y == 0)      { W = w_in; b = b_in; beta = ln1_b; o = b_in_f; rows = 3 * CCH; }
  else if (y == 1) { W = w_fc; b = b_fc; beta = ln2_b; o = b_fc_f; rows = 4 * CCH; }
  else             { int z = y - 2;
                     W = w_attn1 + (long long)z * CCH * CCH; b = b_attn1 + z * CCH;
                     beta = bn3 + z * CCH; o = b_at_f + z * CCH; rows = CCH; }
  if (n >= rows) return;
  const float* Wr = W + (long long)n * CCH;
  float s = 0.f;
  for (int k = threadIdx.x; k < CCH; k += 64) s += Wr[k] * beta[k];
  #pragma unroll
  for (int off = 32; off > 0; off >>= 1) s += __shfl_down(s, off, 64);
  if (threadIdx.x == 0) o[n] = b[n] + s;
}

// plain LayerNorm (no affine), one WAVE per row, shuffle-only
__global__ __launch_bounds__(256) void norm_kernel(
    const float* __restrict__ in, bf16* __restrict__ out, int skipcls, int nrows)
{
  int r = blockIdx.x * 4 + (threadIdx.x >> 6);
  if (r >= nrows) return;
  int lane = threadIdx.x & 63;
  long long ir = skipcls ? tokrow(r) : (long long)r;
  const float* x = in + ir * CCH;
  float v[6];
  float s = 0.f, s2 = 0.f;
  #pragma unroll
  for (int k = 0; k < 6; k++) {
    v[k] = x[lane + k * 64];
    s += v[k]; s2 += v[k] * v[k];
  }
  #pragma unroll
  for (int off = 32; off > 0; off >>= 1) {
    s  += __shfl_xor(s, off, 64);
    s2 += __shfl_xor(s2, off, 64);
  }
  float m = s * (1.0f / CCH);
  float var = s2 * (1.0f / CCH) - m * m;
  float rstd = rsqrtf(var + 1e-5f);
  bf16* o = out + (long long)r * CCH;
  #pragma unroll
  for (int k = 0; k < 6; k++)
    o[lane + k * 64] = __float2bfloat16((v[k] - m) * rstd);
}

// V (within qkv, [s][2C + h*64+d]) -> Vt [bh][d][s padded to 1088], zero tail
__global__ __launch_bounds__(256) void vtrans_kernel(
    const bf16* __restrict__ qkv, bf16* __restrict__ Vt)
{
  __shared__ bf16 tile[64][68];
  int bh = blockIdx.y;
  int b = bh / NHEAD, h = bh % NHEAD;
  int s0 = blockIdx.x * 64;
  int dq = (threadIdx.x & 15) * 4;
  int sl = threadIdx.x >> 4;
  #pragma unroll
  for (int p = 0; p < 4; p++) {
    int sloc = sl + p * 16;
    int s = s0 + sloc;
    uint2 v = make_uint2(0, 0);
    if (s < SEQ)
      v = *reinterpret_cast<const uint2*>(
            qkv + ((long long)(b * SEQ + s)) * (3 * CCH) + 2 * CCH + h * DHEAD + dq);
    *reinterpret_cast<uint2*>(&tile[sloc][dq]) = v;
  }
  __syncthreads();
  #pragma unroll
  for (int p = 0; p < 4; p++) {
    int dloc = sl + p * 16;
    int s4 = dq;
    bf16 t0 = tile[s4 + 0][dloc], t1 = tile[s4 + 1][dloc];
    bf16 t2 = tile[s4 + 2][dloc], t3 = tile[s4 + 3][dloc];
    bf16* dst = Vt + ((long long)bh * DHEAD + dloc) * SEQP + s0 + s4;
    dst[0] = t0; dst[1] = t1; dst[2] = t2; dst[3] = t3;
  }
}

// ---------------------------------------------------------------------------
// Flash attention: grid (17 q-tiles, 48 bh). 4 waves x 16 q-rows.
// ---------------------------------------------------------------------------
__global__ __launch_bounds__(256) void flash_kernel(
    const bf16* __restrict__ qkv, const bf16* __restrict__ Vt,
    bf16* __restrict__ O)
{
  __shared__ uint4 Kt[64 * 9];
  __shared__ uint4 Vtt[64 * 9];
  __shared__ uint4 Pt[64 * 9];
  const int bh = blockIdx.y;
  const int b = bh / NHEAD, h = bh % NHEAD;
  const int q0 = blockIdx.x * 64;
  const int tid = threadIdx.x;
  const int lane = tid & 63, w = tid >> 6;
  const int q = lane >> 4, ln = lane & 15;
  const uint4 zero4 = make_uint4(0, 0, 0, 0);

  short8 aq[2];
  {
    int qrow = q0 + w * 16 + ln;
    #pragma unroll
    for (int ks = 0; ks < 2; ks++) {
      if (qrow < SEQ)
        aq[ks] = *reinterpret_cast<const short8*>(
            qkv + ((long long)(b * SEQ + qrow)) * (3 * CCH) + h * DHEAD + ks * 32 + q * 8);
      else
        aq[ks] = (short8){0, 0, 0, 0, 0, 0, 0, 0};
    }
  }

  floatx4 oacc[4];
  #pragma unroll
  for (int j = 0; j < 4; j++) oacc[j] = (floatx4){0.f, 0.f, 0.f, 0.f};
  float m_i[4], l_i[4];
  #pragma unroll
  for (int r = 0; r < 4; r++) { m_i[r] = -FLT_MAX; l_i[r] = 0.f; }

  for (int kt = 0; kt < SEQP / 64; kt++) {
    __syncthreads();
    #pragma unroll
    for (int p = 0; p < 2; p++) {
      int g = p * 256 + tid;
      int row = g >> 3, k8 = g & 7;
      int sg = kt * 64 + row;
      uint4 kv = zero4;
      if (sg < SEQ)
        kv = *reinterpret_cast<const uint4*>(
              qkv + ((long long)(b * SEQ + sg)) * (3 * CCH) + CCH + h * DHEAD + k8 * 8);
      Kt[row * 9 + k8] = kv;
      Vtt[row * 9 + k8] = *reinterpret_cast<const uint4*>(
              Vt + ((long long)bh * DHEAD + row) * SEQP + kt * 64 + k8 * 8);
    }
    __syncthreads();

    floatx4 sa[4];
    #pragma unroll
    for (int j = 0; j < 4; j++) sa[j] = (floatx4){0.f, 0.f, 0.f, 0.f};
    #pragma unroll
    for (int ks = 0; ks < 2; ks++) {
      #pragma unroll
      for (int j = 0; j < 4; j++) {
        short8 kb = *reinterpret_cast<const short8*>(&Kt[(j * 16 + ln) * 9 + ks * 4 + q]);
        sa[j] = __builtin_amdgcn_mfma_f32_16x16x32_bf16(aq[ks], kb, sa[j], 0, 0, 0);
      }
    }

    bf16* pbase = reinterpret_cast<bf16*>(Pt);
    #pragma unroll
    for (int r = 0; r < 4; r++) {
      float mx = -FLT_MAX;
      #pragma unroll
      for (int j = 0; j < 4; j++) {
        float s = sa[j][r] * 0.125f;
        int key = kt * 64 + j * 16 + ln;
        s = (key < SEQ) ? s : -FLT_MAX;
        sa[j][r] = s;
        mx = fmaxf(mx, s);
      }
      #pragma unroll
      for (int off = 1; off < 16; off <<= 1) mx = fmaxf(mx, __shfl_xor(mx, off, 16));
      float mnew = fmaxf(m_i[r], mx);
      float alpha = __expf(m_i[r] - mnew);
      m_i[r] = mnew;
      float rs = 0.f;
      #pragma unroll
      for (int j = 0; j < 4; j++) {
        float p = __expf(sa[j][r] - mnew);
        sa[j][r] = p;
        rs += p;
      }
      #pragma unroll
      for (int off = 1; off < 16; off <<= 1) rs += __shfl_xor(rs, off, 16);
      l_i[r] = l_i[r] * alpha + rs;
      #pragma unroll
      for (int j = 0; j < 4; j++) oacc[j][r] *= alpha;
      bf16* prow = pbase + (w * 16 + q * 4 + r) * 72;
      #pragma unroll
      for (int j = 0; j < 4; j++) prow[j * 16 + ln] = __float2bfloat16(sa[j][r]);
    }
    #pragma unroll
    for (int ks = 0; ks < 2; ks++) {
      short8 ap = *reinterpret_cast<const short8*>(pbase + (w * 16 + ln) * 72 + ks * 32 + q * 8);
      #pragma unroll
      for (int j = 0; j < 4; j++) {
        short8 vb = *reinterpret_cast<const short8*>(&Vtt[(j * 16 + ln) * 9 + ks * 4 + q]);
        oacc[j] = __builtin_amdgcn_mfma_f32_16x16x32_bf16(ap, vb, oacc[j], 0, 0, 0);
      }
    }
  }

  #pragma unroll
  for (int r = 0; r < 4; r++) {
    int qrow = q0 + w * 16 + q * 4 + r;
    if (qrow >= SEQ) continue;
    float inv = 1.0f / l_i[r];
    bf16* orow = O + ((long long)(b * SEQ + qrow)) * CCH + h * DHEAD;
    #pragma unroll
    for (int j = 0; j < 4; j++)
      orow[j * 16 + ln] = __float2bfloat16(oacc[j][r] * inv);
  }
}

// sorted-segment max+mean over cluster ids; one block per segment
__global__ __launch_bounds__(128) void seg1_kernel(
    const float* __restrict__ x2, const int* __restrict__ sorted_idx,
    const int* __restrict__ seg_id, float* __restrict__ s3)
{
  int s = blockIdx.x;
  int lo = 0, hi = NFEAT;
  while (lo < hi) { int mid = (lo + hi) >> 1; if (seg_id[mid] < s) lo = mid + 1; else hi = mid; }
  int start = lo;
  hi = NFEAT;
  while (lo < hi) { int mid = (lo + hi) >> 1; if (seg_id[mid] < s + 1) lo = mid + 1; else hi = mid; }
  int end = lo;
  int cnt = end - start;
  for (int c = threadIdx.x; c < CCH; c += 128) {
    float sum = 0.f, mx = -FLT_MAX;
    for (int r = start; r < end; r++) {
      int n = sorted_idx[r];
      float v = x2[tokrow(n) * CCH + c];
      sum += v; mx = fmaxf(mx, v);
    }
    float u = (cnt > 0 ? mx : 0.f) + sum / fmaxf((float)cnt, 1.0f);
    s3[(long long)s * CCH + c] = u;
  }
}

// counting sort over flat_grid_index: hist -> scan -> place
__global__ void hist0_kernel(int* __restrict__ cnt)
{
  int idx = blockIdx.x * 256 + threadIdx.x;
  if (idx < NSUP * SEG2) cnt[idx] = 0;
}
__global__ void hist_kernel(const int* __restrict__ fgi, int* __restrict__ cnt)
{
  int idx = blockIdx.x * 256 + threadIdx.x;
  if (idx >= NSUP * NFEAT) return;
  int z = idx >> 13;
  atomicAdd(&cnt[z * SEG2 + fgi[idx]], 1);
}
__global__ __launch_bounds__(256) void scan_kernel(
    const int* __restrict__ cnt, int* __restrict__ base, int* __restrict__ cur)
{
  int z = blockIdx.x, t = threadIdx.x;
  __shared__ int sdata[256];
  const int* c = cnt + z * SEG2;
  int loc[6]; int s = 0;
  #pragma unroll
  for (int e = 0; e < 6; e++) { loc[e] = s; s += c[t * 6 + e]; }
  sdata[t] = s;
  __syncthreads();
  for (int off = 1; off < 256; off <<= 1) {
    int v = (t >= off) ? sdata[t - off] : 0;
    __syncthreads();
    sdata[t] += v;
    __syncthreads();
  }
  int pre = (t > 0) ? sdata[t - 1] : 0;
  #pragma unroll
  for (int e = 0; e < 6; e++) {
    int b = pre + loc[e];
    base[z * SEG2 + t * 6 + e] = b;
    cur[z * SEG2 + t * 6 + e] = b;
  }
}
__global__ void place_kernel(const int* __restrict__ fgi, int* __restrict__ cur,
                             int* __restrict__ order)
{
  int idx = blockIdx.x * 256 + threadIdx.x;
  if (idx >= NSUP * NFEAT) return;
  int z = idx >> 13, n = idx & (NFEAT - 1);
  int s = fgi[idx];
  int pos = atomicAdd(&cur[z * SEG2 + s], 1);
  order[z * NFEAT + pos] = n;
}

// gather-based segment max+mean from fx (bf16) -> u[z][s][c]
__global__ __launch_bounds__(128) void seg2_kernel(
    const bf16* __restrict__ fx, const int* __restrict__ base,
    const int* __restrict__ cnt, const int* __restrict__ order,
    float* __restrict__ u)
{
  int s = blockIdx.x, z = blockIdx.y;
  int st = base[z * SEG2 + s], c = cnt[z * SEG2 + s];
  const int* ord = order + z * NFEAT;
  const bf16* fz = fx + (long long)z * NFEAT * CCH;
  for (int ch = threadIdx.x; ch < CCH; ch += 128) {
    float sum = 0.f, mx = -FLT_MAX;
    for (int r = 0; r < c; r++) {
      float v = __bfloat162float(fz[(long long)ord[st + r] * CCH + ch]);
      sum += v; mx = fmaxf(mx, v);
    }
    u[((long long)z * SEG2 + s) * CCH + ch] = (c > 0 ? mx : 0.f) + sum / fmaxf((float)c, 1.0f);
  }
}

// per-channel batchnorm stats; z-batched
__global__ __launch_bounds__(256) void bnstats_kernel(
    const float* __restrict__ u, long long sU, int rows,
    float* __restrict__ mean, float* __restrict__ var, long long sMV)
{
  int c = blockIdx.x, z = blockIdx.y;
  u += z * sU; mean += z * sMV; var += z * sMV;
  float s = 0.f, s2 = 0.f;
  for (int r = threadIdx.x; r < rows; r += 256) {
    float v = u[(long long)r * CCH + c];
    s += v; s2 += v * v;
  }
  __shared__ float sb[4];
  s  = block_reduce_sum<256>(s, sb);
  s2 = block_reduce_sum<256>(s2, sb);
  if (threadIdx.x == 0) {
    float m = s / rows;
    mean[c] = m;
    var[c] = s2 / rows - m * m;
  }
}

// BN + exact gelu, result + row L2 norm; z-batched
__global__ __launch_bounds__(128) void bnapply_kernel(
    const float* __restrict__ u, long long sU,
    const float* __restrict__ mean, const float* __restrict__ var, long long sMV,
    const float* __restrict__ g, const float* __restrict__ b, long long sGB,
    float* __restrict__ t, long long sT, float* __restrict__ norms, long long sN)
{
  int r = blockIdx.x, z = blockIdx.y;
  u += z * sU; mean += z * sMV; var += z * sMV; g += z * sGB; b += z * sGB;
  t += z * sT; norms += z * sN;
  float ss = 0.f;
  #pragma unroll
  for (int e = 0; e < 3; e++) {
    int c = threadIdx.x + e * 128;
    float v = u[(long long)r * CCH + c];
    float y = (v - mean[c]) * rsqrtf(var[c] + 1e-5f) * g[c] + b[c];
    float ge = 0.5f * y * (1.0f + erff(y * 0.70710678118654752f));
    t[(long long)r * CCH + c] = ge;
    ss += ge * ge;
  }
  __shared__ float sb[2];
  ss = block_reduce_sum<128>(ss, sb);
  if (threadIdx.x == 0) norms[r] = sqrtf(ss);
}

// cosine-sim weighting + final output; one WAVE per row, shuffle-only
__global__ __launch_bounds__(256) void final_kernel(
    const float* __restrict__ x2, const float* __restrict__ t3,
    const float* __restrict__ t3norm, const float* __restrict__ t1d,
    const float* __restrict__ t1dnorm, const int* __restrict__ cluster,
    const int* __restrict__ fgi, float* __restrict__ out)
{
  int row = blockIdx.x * 4 + (threadIdx.x >> 6);
  if (row >= NTOK) return;
  int lane = threadIdx.x & 63;
  int b = row / SEQ, gg = row - b * SEQ;
  const float* xr = x2 + (long long)row * CCH;
  float* orow = out + (long long)row * CCH;
  float xv[6];
  #pragma unroll
  for (int k = 0; k < 6; k++) xv[k] = xr[lane + k * 64];
  if (gg == 0) {
    #pragma unroll
    for (int k = 0; k < 6; k++) orow[lane + k * 64] = xv[k];
    return;
  }
  int n = b * 1024 + gg - 1;
  int c3 = cluster[n];
  const float* a3 = t3 + (long long)c3 * CCH;
  float a3v[6];
  #pragma unroll
  for (int k = 0; k < 6; k++) a3v[k] = a3[lane + k * 64];
  float nb = fmaxf(t3norm[c3], 1e-8f);
  float w[NSUP];
  const float* rows[NSUP];
  float tot = 0.f;
  #pragma unroll
  for (int i = 0; i < NSUP; i++) {
    int s = fgi[i * NFEAT + n];
    const float* ar = t1d + ((long long)i * SEG2 + s) * CCH;
    rows[i] = ar;
    float d = 0.f;
    #pragma unroll
    for (int k = 0; k < 6; k++) d += ar[lane + k * 64] * a3v[k];
    #pragma unroll
    for (int off = 32; off > 0; off >>= 1) d += __shfl_xor(d, off, 64);
    float na = fmaxf(t1dnorm[i * SEG2 + s], 1e-8f);
    float cosv = d / (na * nb);
    w[i] = (cosv + 1.0f) * 0.5f;
    tot += w[i];
  }
  float inv = 1.0f / tot;
  #pragma unroll
  for (int k = 0; k < 6; k++) {
    float acc = 0.f;
    #pragma unroll
    for (int i = 0; i < NSUP; i++) acc += w[i] * rows[i][lane + k * 64];
    orow[lane + k * 64] = xv[k] + 0.3f * acc * inv;
  }
}

extern "C" void kernel_launch(void* const* d_in, const int* in_sizes, int n_in,
                              void* d_out, int out_size, void* d_ws, size_t ws_size,
                              hipStream_t stream)
{
  const float* x_in   = (const float*)d_in[0];
  const float* maskp  = (const float*)d_in[1];
  const float* ln1_g  = (const float*)d_in[2];
  const float* ln1_b  = (const float*)d_in[3];
  const float* ln2_g  = (const float*)d_in[4];
  const float* ln2_b  = (const float*)d_in[5];
  const float* w_in   = (const float*)d_in[6];
  const float* b_in   = (const float*)d_in[7];
  const float* w_out  = (const float*)d_in[8];
  const float* b_out  = (const float*)d_in[9];
  const float* w_fc   = (const float*)d_in[10];
  const float* b_fc   = (const float*)d_in[11];
  const float* w_proj = (const float*)d_in[12];
  const float* b_proj = (const float*)d_in[13];
  const float* wa1    = (const float*)d_in[14];
  const float* ba1    = (const float*)d_in[15];
  const float* wa2    = (const float*)d_in[16];
  const float* ba2    = (const float*)d_in[17];
  const float* g3     = (const float*)d_in[18];
  const float* b3     = (const float*)d_in[19];
  const float* g1d    = (const float*)d_in[20];
  const float* b1d    = (const float*)d_in[21];
  const float* gn3    = (const float*)d_in[22];
  const float* bn3    = (const float*)d_in[23];
  const float* w_attn1= (const float*)d_in[24];
  const float* b_attn1= (const float*)d_in[25];
  const int* sorted_idx = (const int*)d_in[26];
  const int* seg_id   = (const int*)d_in[27];
  const int* cluster  = (const int*)d_in[28];
  const int* fgi      = (const int*)d_in[29];
  float* out = (float*)d_out;
  char* wsb = (char*)d_ws;

  size_t off = 0;
  auto alloc = [&](size_t bytes) { size_t o = off; off += (bytes + 255) & ~(size_t)255; return o; };
  size_t o_qkv  = alloc((size_t)NTOK * 3 * CCH * 2);            // qkv bf16
  size_t o_Vt   = alloc((size_t)NB * NHEAD * DHEAD * SEQP * 2); // Vt; qkv+Vt reused as fc_bf
  size_t o_hbf  = alloc((size_t)NTOK * CCH * 2);                // norm out bf16 (reused 3x)
  size_t o_obf  = alloc((size_t)NTOK * CCH * 2);                // attn out; later ffn_bf
  size_t o_x1   = alloc((size_t)NTOK * CCH * 4);
  size_t o_x2   = alloc((size_t)NTOK * CCH * 4);
  size_t o_ffn  = alloc((size_t)NTOK * CCH * 4);
  size_t o_tbf  = alloc((size_t)NTOK * 64 * 2);                 // adapter t, ld 64 (padded)
  size_t o_fx   = alloc((size_t)NSUP * NFEAT * CCH * 2);        // branch out bf16
  size_t o_s3   = alloc((size_t)MSEG * CCH * 4);
  size_t o_t3   = alloc((size_t)MSEG * CCH * 4);
  size_t o_t3n  = alloc((size_t)MSEG * 4);
  size_t o_mean = alloc((size_t)NSUP * CCH * 4);
  size_t o_var  = alloc((size_t)NSUP * CCH * 4);
  size_t o_ssum = alloc((size_t)NSUP * SEG2 * CCH * 4);
  size_t o_t1d  = alloc((size_t)NSUP * SEG2 * CCH * 4);
  size_t o_t1dn = alloc((size_t)NSUP * SEG2 * 4);
  size_t o_cnt  = alloc((size_t)NSUP * SEG2 * 4);
  size_t o_base = alloc((size_t)NSUP * SEG2 * 4);
  size_t o_cur  = alloc((size_t)NSUP * SEG2 * 4);
  size_t o_ord  = alloc((size_t)NSUP * NFEAT * 4);
  size_t o_wib  = alloc((size_t)3 * CCH * CCH * 2);
  size_t o_wob  = alloc((size_t)CCH * CCH * 2);
  size_t o_wfb  = alloc((size_t)4 * CCH * CCH * 2);
  size_t o_wpb  = alloc((size_t)CCH * 4 * CCH * 2);
  size_t o_wa1b = alloc((size_t)AAD * CCH * 2);
  size_t o_wa2b = alloc((size_t)CCH * 64 * 2);                  // wa2 padded to ld 64
  size_t o_watb = alloc((size_t)NSUP * CCH * CCH * 2);
  size_t o_bib  = alloc((size_t)3 * CCH * 4);
  size_t o_bfb  = alloc((size_t)4 * CCH * 4);
  size_t o_bab  = alloc((size_t)NSUP * CCH * 4);

  bf16*  qkv_bf = (bf16*)(wsb + o_qkv);
  bf16*  Vt     = (bf16*)(wsb + o_Vt);
  bf16*  h_bf   = (bf16*)(wsb + o_hbf);
  bf16*  o_bf   = (bf16*)(wsb + o_obf);
  float* x1     = (float*)(wsb + o_x1);
  float* x2     = (float*)(wsb + o_x2);
  float* ffn    = (float*)(wsb + o_ffn);
  bf16*  t_bf   = (bf16*)(wsb + o_tbf);
  bf16*  fx     = (bf16*)(wsb + o_fx);
  float* s3     = (float*)(wsb + o_s3);
  float* t3     = (float*)(wsb + o_t3);
  float* t3n    = (float*)(wsb + o_t3n);
  float* meanb  = (float*)(wsb + o_mean);
  float* varb   = (float*)(wsb + o_var);
  float* ssum   = (float*)(wsb + o_ssum);
  float* t1d    = (float*)(wsb + o_t1d);
  float* t1dn   = (float*)(wsb + o_t1dn);
  int*   cntb   = (int*)(wsb + o_cnt);
  int*   baseb  = (int*)(wsb + o_base);
  int*   curb   = (int*)(wsb + o_cur);
  int*   ordb   = (int*)(wsb + o_ord);
  bf16*  w_in_b = (bf16*)(wsb + o_wib);
  bf16*  w_out_b= (bf16*)(wsb + o_wob);
  bf16*  w_fc_b = (bf16*)(wsb + o_wfb);
  bf16*  w_pj_b = (bf16*)(wsb + o_wpb);
  bf16*  wa1_b  = (bf16*)(wsb + o_wa1b);
  bf16*  wa2_b  = (bf16*)(wsb + o_wa2b);
  bf16*  wat_b  = (bf16*)(wsb + o_watb);
  float* b_in_f = (float*)(wsb + o_bib);
  float* b_fc_f = (float*)(wsb + o_bfb);
  float* b_at_f = (float*)(wsb + o_bab);
  bf16*  fc_bf  = (bf16*)(wsb + o_qkv);  // qkv+Vt dead after attention
  bf16*  ffn_bf = (bf16*)(wsb + o_obf);  // o_bf dead after out-proj

  // ---- weight prep (2 launches): scale/convert table + bias-fold table ----
  prep_kernel<<<dim3((4 * CCH * CCH / 4 + 255) / 256, 12), 256, 0, stream>>>(
      w_in, ln1_g, w_in_b, w_fc, ln2_g, w_fc_b, w_attn1, gn3, wat_b,
      w_out, w_out_b, w_proj, w_pj_b, wa1, wa1_b, wa2, wa2_b);
  fold_kernel<<<dim3(4 * CCH, 8), 64, 0, stream>>>(
      w_in, b_in, ln1_b, b_in_f, w_fc, b_fc, ln2_b, b_fc_f,
      w_attn1, b_attn1, bn3, b_at_f);
  hipMemsetAsync(t_bf, 0, (size_t)NTOK * 64 * 2, stream);  // zero K-pad cols
  // counting sort of flat_grid_index (static per call)
  hist0_kernel<<<(NSUP * SEG2 + 255) / 256, 256, 0, stream>>>(cntb);
  hist_kernel<<<(NSUP * NFEAT + 255) / 256, 256, 0, stream>>>(fgi, cntb);
  scan_kernel<<<NSUP, 256, 0, stream>>>(cntb, baseb, curb);
  place_kernel<<<(NSUP * NFEAT + 255) / 256, 256, 0, stream>>>(fgi, curb, ordb);

  // 1) plain norm(x) -> h_bf   (gamma folded into w_in)
  norm_kernel<<<(NTOK + 3) / 4, 256, 0, stream>>>(x_in, h_bf, 0, NTOK);
  // 2) qkv = norm(x) @ w_in'^T + b_in'
  mgemm_kernel<2, 2><<<dim3(18, 65, 1), 256, 0, stream>>>(
      h_bf, CCH, 0, w_in_b, CCH, 0, nullptr, 0, 0, qkv_bf, 3 * CCH, 0,
      NTOK, 3 * CCH, CCH, b_in_f, 0, 0, 1.0f, nullptr, 0, nullptr, 0, 0, nullptr, 0);
  // 3) V transpose + flash attention
  vtrans_kernel<<<dim3(SEQP / 64, NB * NHEAD), 256, 0, stream>>>(qkv_bf, Vt);
  flash_kernel<<<dim3(SEQP / 64, NB * NHEAD), 256, 0, stream>>>(qkv_bf, Vt, o_bf);
  // 4) x1 = x + o @ w_out^T + b_out
  mgemm_kernel<2, 2><<<dim3(6, 65, 1), 256, 0, stream>>>(
      o_bf, CCH, 0, w_out_b, CCH, 0, x1, CCH, 0, nullptr, 0, 0,
      NTOK, CCH, CCH, b_out, 0, 0, 1.0f, nullptr, 0, x_in, CCH, 0, nullptr, 0);
  // 5) plain norm(x1) -> h_bf
  norm_kernel<<<(NTOK + 3) / 4, 256, 0, stream>>>(x1, h_bf, 0, NTOK);
  // 6) fc = quick_gelu(norm @ w_fc'^T + b_fc')
  mgemm_kernel<2, 2><<<dim3(24, 65, 1), 256, 0, stream>>>(
      h_bf, CCH, 0, w_fc_b, CCH, 0, nullptr, 0, 0, fc_bf, 4 * CCH, 0,
      NTOK, 4 * CCH, CCH, b_fc_f, 0, 1, 1.0f, nullptr, 0, nullptr, 0, 0, nullptr, 0);
  // 7) x_ffn = fc @ w_proj^T + b_proj
  mgemm_kernel<2, 2><<<dim3(6, 65, 1), 256, 0, stream>>>(
      fc_bf, 4 * CCH, 0, w_pj_b, 4 * CCH, 0, ffn, CCH, 0, ffn_bf, CCH, 0,
      NTOK, CCH, 4 * CCH, b_proj, 0, 0, 1.0f, nullptr, 0, nullptr, 0, 0, nullptr, 0);
  // 8) t = quick_gelu(x_ffn @ wa1^T + ba1)   (ld 64, pad cols pre-zeroed)
  mgemm_kernel<2, 2><<<dim3(1, 65, 1), 256, 0, stream>>>(
      ffn_bf, CCH, 0, wa1_b, CCH, 0, nullptr, 0, 0, t_bf, 64, 0,
      NTOK, AAD, CCH, ba1, 0, 1, 1.0f, nullptr, 0, nullptr, 0, 0, nullptr, 0);
  // 9) x2 = x1 + x_ffn + 0.5*(t @ wa2^T + ba2)   (K padded 48->64)
  mgemm_kernel<2, 2><<<dim3(6, 65, 1), 256, 0, stream>>>(
      t_bf, 64, 0, wa2_b, 64, 0, x2, CCH, 0, nullptr, 0, 0,
      NTOK, CCH, 64, ba2, 0, 0, 0.5f, nullptr, 0, x1, CCH, 0, ffn, CCH);
  // 10) cluster pooling -> BN+gelu table t3
  seg1_kernel<<<MSEG, 128, 0, stream>>>(x2, sorted_idx, seg_id, s3);
  bnstats_kernel<<<dim3(CCH, 1), 256, 0, stream>>>(s3, 0, MSEG, meanb, varb, 0);
  bnapply_kernel<<<dim3(MSEG, 1), 128, 0, stream>>>(s3, 0, meanb, varb, 0,
      g3, b3, 0, t3, 0, t3n, 0);
  // 11) branches: shared plain norm of x2, z-batched GEMM (gamma folded) -> fx
  norm_kernel<<<(NFEAT + 3) / 4, 256, 0, stream>>>(x2, h_bf, 1, NFEAT);
  mgemm_kernel<2, 2><<<dim3(6, 64, NSUP), 256, 0, stream>>>(
      h_bf, CCH, 0, wat_b, CCH, (long long)CCH * CCH,
      nullptr, 0, 0, fx, CCH, (long long)NFEAT * CCH,
      NFEAT, CCH, CCH, b_at_f, CCH, 0, 1.0f, maskp, NFEAT, x2, CCH, 1, nullptr, 0);
  // 12) gather-based segment max+mean, then BN+gelu
  seg2_kernel<<<dim3(SEG2, NSUP), 128, 0, stream>>>(fx, baseb, cntb, ordb, ssum);
  bnstats_kernel<<<dim3(CCH, NSUP), 256, 0, stream>>>(
      ssum, (long long)SEG2 * CCH, SEG2, meanb, varb, CCH);
  bnapply_kernel<<<dim3(SEG2, NSUP), 128, 0, stream>>>(
      ssum, (long long)SEG2 * CCH, meanb, varb, CCH,
      g1d, b1d, CCH, t1d, (long long)SEG2 * CCH, t1dn, SEG2);
  // 13) cosine weighting + output
  final_kernel<<<(NTOK + 3) / 4, 256, 0, stream>>>(
      x2, t3, t3n, t1d, t1dn, cluster, fgi, out);
}

// Round 9
// 567.120 us; speedup vs baseline: 1.4326x; 1.4326x over previous
//
#include <hip/hip_runtime.h>
#include <hip/hip_bf16.h>
#include <float.h>
#include <math.h>

#define NB 8
#define CCH 384
#define NHEAD 6
#define DHEAD 64
#define AAD 48
#define MSEG 1024
#define NSUP 6
#define NTOK 8200
#define NFEAT 8192
#define SEG2 1536
#define SEQ 1025
#define SEQP 1088

typedef __hip_bfloat16 bf16;
typedef __attribute__((ext_vector_type(8))) short short8;
typedef __attribute__((ext_vector_type(4))) float floatx4;

// feat row n (0..8191) -> row index in (B,1025,C) token array, skipping CLS
static __device__ __forceinline__ long long tokrow(int n) {
  return (long long)n + (n >> 10) + 1;
}

template<int NT>
static __device__ __forceinline__ float block_reduce_sum(float v, float* s) {
  #pragma unroll
  for (int off = 32; off > 0; off >>= 1) v += __shfl_down(v, off, 64);
  int lane = threadIdx.x & 63, wid = threadIdx.x >> 6;
  if (lane == 0) s[wid] = v;
  __syncthreads();
  if (threadIdx.x == 0) {
    float t = s[0];
    #pragma unroll
    for (int w = 1; w < NT / 64; w++) t += s[w];
    s[0] = t;
  }
  __syncthreads();
  float r = s[0];
  __syncthreads();
  return r;
}

// async global->LDS 16B copy (width=16 verified on gfx950, learn_hip m97)
static __device__ __forceinline__ void async_copy16(void* lds, const void* g) {
  __builtin_amdgcn_global_load_lds(
      (const __attribute__((address_space(1))) unsigned int*)g,
      (__attribute__((address_space(3))) unsigned int*)lds, 16, 0, 0);
}

// ---------------------------------------------------------------------------
// MFMA bf16 GEMM:  C[m,n] = sum_k A[m,k] * Bt[n,k]  (Bt: N x K)
// R7 DMA structure, occupancy-tuned: wave tile 64x32 (acc = 32 VGPR),
// block tile (WM*64) x (WN*32) = 128x64 at <2,2>. BK=64, single 24KB LDS.
// Async global_load_lds staging (NO staging registers -> no spill), XOR
// granule swizzle (slot g holds global granule g^(row&7)) -> conflict-free
// ds_read_b128. Fast DMA path when tile in-bounds and K%64==0; guarded
// register path otherwise.
// ---------------------------------------------------------------------------
template<int WM, int WN>
__global__ __launch_bounds__(256) void mgemm_kernel(
    const bf16* __restrict__ A, int lda, long long sAh,
    const bf16* __restrict__ B, int ldb, long long sBh,
    float* __restrict__ outF, int ldcF, long long sCFh,
    bf16* __restrict__ outB, int ldcB, long long sCBh,
    int M, int N, int K,
    const float* __restrict__ bias, long long sBias, int act, float scale,
    const float* __restrict__ rowmask, long long sMask,
    const float* __restrict__ res1, int ldr1, int res1skip,
    const float* __restrict__ res2, int ldr2)
{
  constexpr int BM = WM * 64, BN = WN * 32;
  __shared__ uint4 Asg[BM * 8];
  __shared__ uint4 Bsg[BN * 8];
  const int z = blockIdx.z;
  const bf16* Ap = A + (long long)z * sAh;
  const bf16* Bp = B + (long long)z * sBh;
  const int tid = threadIdx.x;
  const int m0 = blockIdx.y * BM, n0 = blockIdx.x * BN;
  const int lane = tid & 63, wid = tid >> 6;
  const int wm = (wid % WM) * 64, wn = (wid / WM) * 32;
  const int q = lane >> 4, ln = lane & 15;
  const uint4 zero4 = make_uint4(0, 0, 0, 0);

  const bool fastK = ((K & 63) == 0);
  const bool fastA = fastK && (m0 + BM <= M);
  const bool fastB = fastK && (n0 + BN <= N);

  floatx4 acc[4][2];
  #pragma unroll
  for (int i = 0; i < 4; i++)
    #pragma unroll
    for (int j = 0; j < 2; j++) acc[i][j] = (floatx4){0.f, 0.f, 0.f, 0.f};

  const int nk = (K + 63) >> 6;
  for (int t = 0; t < nk; t++) {
    const int k0 = t * 64;
    __syncthreads();
    if (fastA) {
      #pragma unroll
      for (int p = 0; p < 2 * WM; p++) {
        int idx = p * 256 + tid;
        int row = idx >> 3, g = idx & 7;
        int gs = g ^ (row & 7);
        async_copy16(&Asg[p * 256 + wid * 64],
                     Ap + (long long)(m0 + row) * lda + k0 + gs * 8);
      }
    } else {
      #pragma unroll
      for (int p = 0; p < 2 * WM; p++) {
        int idx = p * 256 + tid;
        int row = idx >> 3, g = idx & 7;
        int gs = g ^ (row & 7);
        int gm = m0 + row, gk = k0 + gs * 8;
        uint4 v = zero4;
        if (gm < M && gk < K)
          v = *reinterpret_cast<const uint4*>(Ap + (long long)gm * lda + gk);
        Asg[idx] = v;
      }
    }
    if (fastB) {
      #pragma unroll
      for (int p = 0; p < WN; p++) {
        int idx = p * 256 + tid;
        int row = idx >> 3, g = idx & 7;
        int gs = g ^ (row & 7);
        async_copy16(&Bsg[p * 256 + wid * 64],
                     Bp + (long long)(n0 + row) * ldb + k0 + gs * 8);
      }
    } else {
      #pragma unroll
      for (int p = 0; p < WN; p++) {
        int idx = p * 256 + tid;
        int row = idx >> 3, g = idx & 7;
        int gs = g ^ (row & 7);
        int gn = n0 + row, gk = k0 + gs * 8;
        uint4 v = zero4;
        if (gn < N && gk < K)
          v = *reinterpret_cast<const uint4*>(Bp + (long long)gn * ldb + gk);
        Bsg[idx] = v;
      }
    }
    asm volatile("s_waitcnt vmcnt(0)" ::: "memory");
    __syncthreads();
    #pragma unroll
    for (int ks = 0; ks < 2; ks++) {
      short8 af[4], bfr[2];
      #pragma unroll
      for (int i = 0; i < 4; i++) {
        int row = wm + i * 16 + ln;
        af[i] = *reinterpret_cast<const short8*>(
            &Asg[row * 8 + ((ks * 4 + q) ^ (ln & 7))]);
      }
      #pragma unroll
      for (int j = 0; j < 2; j++) {
        int row = wn + j * 16 + ln;
        bfr[j] = *reinterpret_cast<const short8*>(
            &Bsg[row * 8 + ((ks * 4 + q) ^ (ln & 7))]);
      }
      #pragma unroll
      for (int i = 0; i < 4; i++)
        #pragma unroll
        for (int j = 0; j < 2; j++)
          acc[i][j] = __builtin_amdgcn_mfma_f32_16x16x32_bf16(af[i], bfr[j], acc[i][j], 0, 0, 0);
    }
  }

  const float* biasz = bias ? bias + z * sBias : nullptr;
  const float* rmz = rowmask ? rowmask + z * sMask : nullptr;
  float* cF = outF ? outF + (long long)z * sCFh : nullptr;
  bf16*  cB = outB ? outB + (long long)z * sCBh : nullptr;
  #pragma unroll
  for (int i = 0; i < 4; i++) {
    #pragma unroll
    for (int r = 0; r < 4; r++) {
      int gm = m0 + wm + i * 16 + q * 4 + r;
      if (gm >= M) continue;
      float rm = rmz ? rmz[gm] : 1.0f;
      long long r1off = 0;
      if (res1) r1off = (res1skip ? tokrow(gm) : (long long)gm) * ldr1;
      #pragma unroll
      for (int j = 0; j < 2; j++) {
        int gn = n0 + wn + j * 16 + ln;
        if (gn >= N) continue;
        float v = acc[i][j][r];
        if (biasz) v += biasz[gn];
        if (act) v = v / (1.0f + __expf(-1.702f * v));  // quick_gelu
        v *= scale * rm;
        if (res1) v += res1[r1off + gn];
        if (res2) v += res2[(long long)gm * ldr2 + gn];
        if (cF) cF[(long long)gm * ldcF + gn] = v;
        if (cB) cB[(long long)gm * ldcB + gn] = __float2bfloat16(v);
      }
    }
  }
}

// ---------------------------------------------------------------------------
// Unified weight-prep kernel (table over blockIdx.y):
//  y=0: w_in*ln1_g  y=1: w_fc*ln2_g  y=2..7: w_attn1[z]*gn3[z]
//  y=8: w_out  y=9: w_proj  y=10: wa1  y=11: wa2 padded to ld 64
// ---------------------------------------------------------------------------
__global__ void prep_kernel(
    const float* __restrict__ w_in, const float* __restrict__ ln1_g, bf16* __restrict__ w_in_b,
    const float* __restrict__ w_fc, const float* __restrict__ ln2_g, bf16* __restrict__ w_fc_b,
    const float* __restrict__ w_attn1, const float* __restrict__ gn3, bf16* __restrict__ wat_b,
    const float* __restrict__ w_out, bf16* __restrict__ w_out_b,
    const float* __restrict__ w_proj, bf16* __restrict__ w_pj_b,
    const float* __restrict__ wa1, bf16* __restrict__ wa1_b,
    const float* __restrict__ wa2, bf16* __restrict__ wa2_b)
{
  int y = blockIdx.y;
  int i = (blockIdx.x * 256 + threadIdx.x) * 4;
  if (y == 11) {
    if (i >= CCH * 64) return;
    int r = i >> 6, c = i & 63;
    #pragma unroll
    for (int e = 0; e < 4; e++)
      wa2_b[i + e] = __float2bfloat16((c + e) < AAD ? wa2[r * AAD + c + e] : 0.f);
    return;
  }
  const float* s; bf16* d; const float* g = nullptr; int n;
  if (y == 0)      { s = w_in;  d = w_in_b;  g = ln1_g; n = 3 * CCH * CCH; }
  else if (y == 1) { s = w_fc;  d = w_fc_b;  g = ln2_g; n = 4 * CCH * CCH; }
  else if (y <= 7) { int z = y - 2;
                     s = w_attn1 + (long long)z * CCH * CCH;
                     d = wat_b   + (long long)z * CCH * CCH;
                     g = gn3 + z * CCH; n = CCH * CCH; }
  else if (y == 8) { s = w_out;  d = w_out_b; n = CCH * CCH; }
  else if (y == 9) { s = w_proj; d = w_pj_b;  n = 4 * CCH * CCH; }
  else             { s = wa1;   d = wa1_b;   n = AAD * CCH; }
  if (i >= n) return;
  float4 v = *reinterpret_cast<const float4*>(s + i);
  if (g) {
    int k = i % CCH;
    v.x *= g[k]; v.y *= g[k + 1]; v.z *= g[k + 2]; v.w *= g[k + 3];
  }
  d[i]     = __float2bfloat16(v.x);
  d[i + 1] = __float2bfloat16(v.y);
  d[i + 2] = __float2bfloat16(v.z);
  d[i + 3] = __float2bfloat16(v.w);
}

// Unified bias-fold: out[n] = b[n] + sum_k beta[k] * W[n][k]; one wave/row.
__global__ __launch_bounds__(64) void fold_kernel(
    const float* __restrict__ w_in, const float* __restrict__ b_in,
    const float* __restrict__ ln1_b, float* __restrict__ b_in_f,
    const float* __restrict__ w_fc, const float* __restrict__ b_fc,
    const float* __restrict__ ln2_b, float* __restrict__ b_fc_f,
    const float* __restrict__ w_attn1, const float* __restrict__ b_attn1,
    const float* __restrict__ bn3, float* __restrict__ b_at_f)
{
  int y = blockIdx.y, n = blockIdx.x;
  const float* W; const float* b; const float* beta; float* o; int rows;
  if (y == 0)      { W = w_in; b = b_in; beta = ln1_b; o = b_in_f; rows = 3 * CCH; }
  else if (y == 1) { W = w_fc; b = b_fc; beta = ln2_b; o = b_fc_f; rows = 4 * CCH; }
  else             { int z = y - 2;
                     W = w_attn1 + (long long)z * CCH * CCH; b = b_attn1 + z * CCH;
                     beta = bn3 + z * CCH; o = b_at_f + z * CCH; rows = CCH; }
  if (n >= rows) return;
  const float* Wr = W + (long long)n * CCH;
  float s = 0.f;
  for (int k = threadIdx.x; k < CCH; k += 64) s += Wr[k] * beta[k];
  #pragma unroll
  for (int off = 32; off > 0; off >>= 1) s += __shfl_down(s, off, 64);
  if (threadIdx.x == 0) o[n] = b[n] + s;
}

// plain LayerNorm (no affine), one WAVE per row, shuffle-only
__global__ __launch_bounds__(256) void norm_kernel(
    const float* __restrict__ in, bf16* __restrict__ out, int skipcls, int nrows)
{
  int r = blockIdx.x * 4 + (threadIdx.x >> 6);
  if (r >= nrows) return;
  int lane = threadIdx.x & 63;
  long long ir = skipcls ? tokrow(r) : (long long)r;
  const float* x = in + ir * CCH;
  float v[6];
  float s = 0.f, s2 = 0.f;
  #pragma unroll
  for (int k = 0; k < 6; k++) {
    v[k] = x[lane + k * 64];
    s += v[k]; s2 += v[k] * v[k];
  }
  #pragma unroll
  for (int off = 32; off > 0; off >>= 1) {
    s  += __shfl_xor(s, off, 64);
    s2 += __shfl_xor(s2, off, 64);
  }
  float m = s * (1.0f / CCH);
  float var = s2 * (1.0f / CCH) - m * m;
  float rstd = rsqrtf(var + 1e-5f);
  bf16* o = out + (long long)r * CCH;
  #pragma unroll
  for (int k = 0; k < 6; k++)
    o[lane + k * 64] = __float2bfloat16((v[k] - m) * rstd);
}

// V (within qkv, [s][2C + h*64+d]) -> Vt [bh][d][s padded to 1088], zero tail
__global__ __launch_bounds__(256) void vtrans_kernel(
    const bf16* __restrict__ qkv, bf16* __restrict__ Vt)
{
  __shared__ bf16 tile[64][68];
  int bh = blockIdx.y;
  int b = bh / NHEAD, h = bh % NHEAD;
  int s0 = blockIdx.x * 64;
  int dq = (threadIdx.x & 15) * 4;
  int sl = threadIdx.x >> 4;
  #pragma unroll
  for (int p = 0; p < 4; p++) {
    int sloc = sl + p * 16;
    int s = s0 + sloc;
    uint2 v = make_uint2(0, 0);
    if (s < SEQ)
      v = *reinterpret_cast<const uint2*>(
            qkv + ((long long)(b * SEQ + s)) * (3 * CCH) + 2 * CCH + h * DHEAD + dq);
    *reinterpret_cast<uint2*>(&tile[sloc][dq]) = v;
  }
  __syncthreads();
  #pragma unroll
  for (int p = 0; p < 4; p++) {
    int dloc = sl + p * 16;
    int s4 = dq;
    bf16 t0 = tile[s4 + 0][dloc], t1 = tile[s4 + 1][dloc];
    bf16 t2 = tile[s4 + 2][dloc], t3 = tile[s4 + 3][dloc];
    bf16* dst = Vt + ((long long)bh * DHEAD + dloc) * SEQP + s0 + s4;
    dst[0] = t0; dst[1] = t1; dst[2] = t2; dst[3] = t3;
  }
}

// ---------------------------------------------------------------------------
// Flash attention: grid (17 q-tiles, 48 bh). 4 waves x 16 q-rows.
// ---------------------------------------------------------------------------
__global__ __launch_bounds__(256) void flash_kernel(
    const bf16* __restrict__ qkv, const bf16* __restrict__ Vt,
    bf16* __restrict__ O)
{
  __shared__ uint4 Kt[64 * 9];
  __shared__ uint4 Vtt[64 * 9];
  __shared__ uint4 Pt[64 * 9];
  const int bh = blockIdx.y;
  const int b = bh / NHEAD, h = bh % NHEAD;
  const int q0 = blockIdx.x * 64;
  const int tid = threadIdx.x;
  const int lane = tid & 63, w = tid >> 6;
  const int q = lane >> 4, ln = lane & 15;
  const uint4 zero4 = make_uint4(0, 0, 0, 0);

  short8 aq[2];
  {
    int qrow = q0 + w * 16 + ln;
    #pragma unroll
    for (int ks = 0; ks < 2; ks++) {
      if (qrow < SEQ)
        aq[ks] = *reinterpret_cast<const short8*>(
            qkv + ((long long)(b * SEQ + qrow)) * (3 * CCH) + h * DHEAD + ks * 32 + q * 8);
      else
        aq[ks] = (short8){0, 0, 0, 0, 0, 0, 0, 0};
    }
  }

  floatx4 oacc[4];
  #pragma unroll
  for (int j = 0; j < 4; j++) oacc[j] = (floatx4){0.f, 0.f, 0.f, 0.f};
  float m_i[4], l_i[4];
  #pragma unroll
  for (int r = 0; r < 4; r++) { m_i[r] = -FLT_MAX; l_i[r] = 0.f; }

  for (int kt = 0; kt < SEQP / 64; kt++) {
    __syncthreads();
    #pragma unroll
    for (int p = 0; p < 2; p++) {
      int g = p * 256 + tid;
      int row = g >> 3, k8 = g & 7;
      int sg = kt * 64 + row;
      uint4 kv = zero4;
      if (sg < SEQ)
        kv = *reinterpret_cast<const uint4*>(
              qkv + ((long long)(b * SEQ + sg)) * (3 * CCH) + CCH + h * DHEAD + k8 * 8);
      Kt[row * 9 + k8] = kv;
      Vtt[row * 9 + k8] = *reinterpret_cast<const uint4*>(
              Vt + ((long long)bh * DHEAD + row) * SEQP + kt * 64 + k8 * 8);
    }
    __syncthreads();

    floatx4 sa[4];
    #pragma unroll
    for (int j = 0; j < 4; j++) sa[j] = (floatx4){0.f, 0.f, 0.f, 0.f};
    #pragma unroll
    for (int ks = 0; ks < 2; ks++) {
      #pragma unroll
      for (int j = 0; j < 4; j++) {
        short8 kb = *reinterpret_cast<const short8*>(&Kt[(j * 16 + ln) * 9 + ks * 4 + q]);
        sa[j] = __builtin_amdgcn_mfma_f32_16x16x32_bf16(aq[ks], kb, sa[j], 0, 0, 0);
      }
    }

    bf16* pbase = reinterpret_cast<bf16*>(Pt);
    #pragma unroll
    for (int r = 0; r < 4; r++) {
      float mx = -FLT_MAX;
      #pragma unroll
      for (int j = 0; j < 4; j++) {
        float s = sa[j][r] * 0.125f;
        int key = kt * 64 + j * 16 + ln;
        s = (key < SEQ) ? s : -FLT_MAX;
        sa[j][r] = s;
        mx = fmaxf(mx, s);
      }
      #pragma unroll
      for (int off = 1; off < 16; off <<= 1) mx = fmaxf(mx, __shfl_xor(mx, off, 16));
      float mnew = fmaxf(m_i[r], mx);
      float alpha = __expf(m_i[r] - mnew);
      m_i[r] = mnew;
      float rs = 0.f;
      #pragma unroll
      for (int j = 0; j < 4; j++) {
        float p = __expf(sa[j][r] - mnew);
        sa[j][r] = p;
        rs += p;
      }
      #pragma unroll
      for (int off = 1; off < 16; off <<= 1) rs += __shfl_xor(rs, off, 16);
      l_i[r] = l_i[r] * alpha + rs;
      #pragma unroll
      for (int j = 0; j < 4; j++) oacc[j][r] *= alpha;
      bf16* prow = pbase + (w * 16 + q * 4 + r) * 72;
      #pragma unroll
      for (int j = 0; j < 4; j++) prow[j * 16 + ln] = __float2bfloat16(sa[j][r]);
    }
    #pragma unroll
    for (int ks = 0; ks < 2; ks++) {
      short8 ap = *reinterpret_cast<const short8*>(pbase + (w * 16 + ln) * 72 + ks * 32 + q * 8);
      #pragma unroll
      for (int j = 0; j < 4; j++) {
        short8 vb = *reinterpret_cast<const short8*>(&Vtt[(j * 16 + ln) * 9 + ks * 4 + q]);
        oacc[j] = __builtin_amdgcn_mfma_f32_16x16x32_bf16(ap, vb, oacc[j], 0, 0, 0);
      }
    }
  }

  #pragma unroll
  for (int r = 0; r < 4; r++) {
    int qrow = q0 + w * 16 + q * 4 + r;
    if (qrow >= SEQ) continue;
    float inv = 1.0f / l_i[r];
    bf16* orow = O + ((long long)(b * SEQ + qrow)) * CCH + h * DHEAD;
    #pragma unroll
    for (int j = 0; j < 4; j++)
      orow[j * 16 + ln] = __float2bfloat16(oacc[j][r] * inv);
  }
}

// sorted-segment max+mean over cluster ids; one block per segment
__global__ __launch_bounds__(128) void seg1_kernel(
    const float* __restrict__ x2, const int* __restrict__ sorted_idx,
    const int* __restrict__ seg_id, float* __restrict__ s3)
{
  int s = blockIdx.x;
  int lo = 0, hi = NFEAT;
  while (lo < hi) { int mid = (lo + hi) >> 1; if (seg_id[mid] < s) lo = mid + 1; else hi = mid; }
  int start = lo;
  hi = NFEAT;
  while (lo < hi) { int mid = (lo + hi) >> 1; if (seg_id[mid] < s + 1) lo = mid + 1; else hi = mid; }
  int end = lo;
  int cnt = end - start;
  for (int c = threadIdx.x; c < CCH; c += 128) {
    float sum = 0.f, mx = -FLT_MAX;
    for (int r = start; r < end; r++) {
      int n = sorted_idx[r];
      float v = x2[tokrow(n) * CCH + c];
      sum += v; mx = fmaxf(mx, v);
    }
    float u = (cnt > 0 ? mx : 0.f) + sum / fmaxf((float)cnt, 1.0f);
    s3[(long long)s * CCH + c] = u;
  }
}

// counting sort over flat_grid_index: hist -> scan -> place
__global__ void hist0_kernel(int* __restrict__ cnt)
{
  int idx = blockIdx.x * 256 + threadIdx.x;
  if (idx < NSUP * SEG2) cnt[idx] = 0;
}
__global__ void hist_kernel(const int* __restrict__ fgi, int* __restrict__ cnt)
{
  int idx = blockIdx.x * 256 + threadIdx.x;
  if (idx >= NSUP * NFEAT) return;
  int z = idx >> 13;
  atomicAdd(&cnt[z * SEG2 + fgi[idx]], 1);
}
__global__ __launch_bounds__(256) void scan_kernel(
    const int* __restrict__ cnt, int* __restrict__ base, int* __restrict__ cur)
{
  int z = blockIdx.x, t = threadIdx.x;
  __shared__ int sdata[256];
  const int* c = cnt + z * SEG2;
  int loc[6]; int s = 0;
  #pragma unroll
  for (int e = 0; e < 6; e++) { loc[e] = s; s += c[t * 6 + e]; }
  sdata[t] = s;
  __syncthreads();
  for (int off = 1; off < 256; off <<= 1) {
    int v = (t >= off) ? sdata[t - off] : 0;
    __syncthreads();
    sdata[t] += v;
    __syncthreads();
  }
  int pre = (t > 0) ? sdata[t - 1] : 0;
  #pragma unroll
  for (int e = 0; e < 6; e++) {
    int b = pre + loc[e];
    base[z * SEG2 + t * 6 + e] = b;
    cur[z * SEG2 + t * 6 + e] = b;
  }
}
__global__ void place_kernel(const int* __restrict__ fgi, int* __restrict__ cur,
                             int* __restrict__ order)
{
  int idx = blockIdx.x * 256 + threadIdx.x;
  if (idx >= NSUP * NFEAT) return;
  int z = idx >> 13, n = idx & (NFEAT - 1);
  int s = fgi[idx];
  int pos = atomicAdd(&cur[z * SEG2 + s], 1);
  order[z * NFEAT + pos] = n;
}

// gather-based segment max+mean from fx (bf16) -> u[z][s][c]
__global__ __launch_bounds__(128) void seg2_kernel(
    const bf16* __restrict__ fx, const int* __restrict__ base,
    const int* __restrict__ cnt, const int* __restrict__ order,
    float* __restrict__ u)
{
  int s = blockIdx.x, z = blockIdx.y;
  int st = base[z * SEG2 + s], c = cnt[z * SEG2 + s];
  const int* ord = order + z * NFEAT;
  const bf16* fz = fx + (long long)z * NFEAT * CCH;
  for (int ch = threadIdx.x; ch < CCH; ch += 128) {
    float sum = 0.f, mx = -FLT_MAX;
    for (int r = 0; r < c; r++) {
      float v = __bfloat162float(fz[(long long)ord[st + r] * CCH + ch]);
      sum += v; mx = fmaxf(mx, v);
    }
    u[((long long)z * SEG2 + s) * CCH + ch] = (c > 0 ? mx : 0.f) + sum / fmaxf((float)c, 1.0f);
  }
}

// per-channel batchnorm stats; z-batched
__global__ __launch_bounds__(256) void bnstats_kernel(
    const float* __restrict__ u, long long sU, int rows,
    float* __restrict__ mean, float* __restrict__ var, long long sMV)
{
  int c = blockIdx.x, z = blockIdx.y;
  u += z * sU; mean += z * sMV; var += z * sMV;
  float s = 0.f, s2 = 0.f;
  for (int r = threadIdx.x; r < rows; r += 256) {
    float v = u[(long long)r * CCH + c];
    s += v; s2 += v * v;
  }
  __shared__ float sb[4];
  s  = block_reduce_sum<256>(s, sb);
  s2 = block_reduce_sum<256>(s2, sb);
  if (threadIdx.x == 0) {
    float m = s / rows;
    mean[c] = m;
    var[c] = s2 / rows - m * m;
  }
}

// BN + exact gelu, result + row L2 norm; z-batched
__global__ __launch_bounds__(128) void bnapply_kernel(
    const float* __restrict__ u, long long sU,
    const float* __restrict__ mean, const float* __restrict__ var, long long sMV,
    const float* __restrict__ g, const float* __restrict__ b, long long sGB,
    float* __restrict__ t, long long sT, float* __restrict__ norms, long long sN)
{
  int r = blockIdx.x, z = blockIdx.y;
  u += z * sU; mean += z * sMV; var += z * sMV; g += z * sGB; b += z * sGB;
  t += z * sT; norms += z * sN;
  float ss = 0.f;
  #pragma unroll
  for (int e = 0; e < 3; e++) {
    int c = threadIdx.x + e * 128;
    float v = u[(long long)r * CCH + c];
    float y = (v - mean[c]) * rsqrtf(var[c] + 1e-5f) * g[c] + b[c];
    float ge = 0.5f * y * (1.0f + erff(y * 0.70710678118654752f));
    t[(long long)r * CCH + c] = ge;
    ss += ge * ge;
  }
  __shared__ float sb[2];
  ss = block_reduce_sum<128>(ss, sb);
  if (threadIdx.x == 0) norms[r] = sqrtf(ss);
}

// cosine-sim weighting + final output; one WAVE per row, shuffle-only
__global__ __launch_bounds__(256) void final_kernel(
    const float* __restrict__ x2, const float* __restrict__ t3,
    const float* __restrict__ t3norm, const float* __restrict__ t1d,
    const float* __restrict__ t1dnorm, const int* __restrict__ cluster,
    const int* __restrict__ fgi, float* __restrict__ out)
{
  int row = blockIdx.x * 4 + (threadIdx.x >> 6);
  if (row >= NTOK) return;
  int lane = threadIdx.x & 63;
  int b = row / SEQ, gg = row - b * SEQ;
  const float* xr = x2 + (long long)row * CCH;
  float* orow = out + (long long)row * CCH;
  float xv[6];
  #pragma unroll
  for (int k = 0; k < 6; k++) xv[k] = xr[lane + k * 64];
  if (gg == 0) {
    #pragma unroll
    for (int k = 0; k < 6; k++) orow[lane + k * 64] = xv[k];
    return;
  }
  int n = b * 1024 + gg - 1;
  int c3 = cluster[n];
  const float* a3 = t3 + (long long)c3 * CCH;
  float a3v[6];
  #pragma unroll
  for (int k = 0; k < 6; k++) a3v[k] = a3[lane + k * 64];
  float nb = fmaxf(t3norm[c3], 1e-8f);
  float w[NSUP];
  const float* rows[NSUP];
  float tot = 0.f;
  #pragma unroll
  for (int i = 0; i < NSUP; i++) {
    int s = fgi[i * NFEAT + n];
    const float* ar = t1d + ((long long)i * SEG2 + s) * CCH;
    rows[i] = ar;
    float d = 0.f;
    #pragma unroll
    for (int k = 0; k < 6; k++) d += ar[lane + k * 64] * a3v[k];
    #pragma unroll
    for (int off = 32; off > 0; off >>= 1) d += __shfl_xor(d, off, 64);
    float na = fmaxf(t1dnorm[i * SEG2 + s], 1e-8f);
    float cosv = d / (na * nb);
    w[i] = (cosv + 1.0f) * 0.5f;
    tot += w[i];
  }
  float inv = 1.0f / tot;
  #pragma unroll
  for (int k = 0; k < 6; k++) {
    float acc = 0.f;
    #pragma unroll
    for (int i = 0; i < NSUP; i++) acc += w[i] * rows[i][lane + k * 64];
    orow[lane + k * 64] = xv[k] + 0.3f * acc * inv;
  }
}

extern "C" void kernel_launch(void* const* d_in, const int* in_sizes, int n_in,
                              void* d_out, int out_size, void* d_ws, size_t ws_size,
                              hipStream_t stream)
{
  const float* x_in   = (const float*)d_in[0];
  const float* maskp  = (const float*)d_in[1];
  const float* ln1_g  = (const float*)d_in[2];
  const float* ln1_b  = (const float*)d_in[3];
  const float* ln2_g  = (const float*)d_in[4];
  const float* ln2_b  = (const float*)d_in[5];
  const float* w_in   = (const float*)d_in[6];
  const float* b_in   = (const float*)d_in[7];
  const float* w_out  = (const float*)d_in[8];
  const float* b_out  = (const float*)d_in[9];
  const float* w_fc   = (const float*)d_in[10];
  const float* b_fc   = (const float*)d_in[11];
  const float* w_proj = (const float*)d_in[12];
  const float* b_proj = (const float*)d_in[13];
  const float* wa1    = (const float*)d_in[14];
  const float* ba1    = (const float*)d_in[15];
  const float* wa2    = (const float*)d_in[16];
  const float* ba2    = (const float*)d_in[17];
  const float* g3     = (const float*)d_in[18];
  const float* b3     = (const float*)d_in[19];
  const float* g1d    = (const float*)d_in[20];
  const float* b1d    = (const float*)d_in[21];
  const float* gn3    = (const float*)d_in[22];
  const float* bn3    = (const float*)d_in[23];
  const float* w_attn1= (const float*)d_in[24];
  const float* b_attn1= (const float*)d_in[25];
  const int* sorted_idx = (const int*)d_in[26];
  const int* seg_id   = (const int*)d_in[27];
  const int* cluster  = (const int*)d_in[28];
  const int* fgi      = (const int*)d_in[29];
  float* out = (float*)d_out;
  char* wsb = (char*)d_ws;

  size_t off = 0;
  auto alloc = [&](size_t bytes) { size_t o = off; off += (bytes + 255) & ~(size_t)255; return o; };
  size_t o_qkv  = alloc((size_t)NTOK * 3 * CCH * 2);            // qkv bf16
  size_t o_Vt   = alloc((size_t)NB * NHEAD * DHEAD * SEQP * 2); // Vt; qkv+Vt reused as fc_bf
  size_t o_hbf  = alloc((size_t)NTOK * CCH * 2);                // norm out bf16 (reused 3x)
  size_t o_obf  = alloc((size_t)NTOK * CCH * 2);                // attn out; later ffn_bf
  size_t o_x1   = alloc((size_t)NTOK * CCH * 4);
  size_t o_x2   = alloc((size_t)NTOK * CCH * 4);
  size_t o_ffn  = alloc((size_t)NTOK * CCH * 4);
  size_t o_tbf  = alloc((size_t)NTOK * 64 * 2);                 // adapter t, ld 64 (padded)
  size_t o_fx   = alloc((size_t)NSUP * NFEAT * CCH * 2);        // branch out bf16
  size_t o_s3   = alloc((size_t)MSEG * CCH * 4);
  size_t o_t3   = alloc((size_t)MSEG * CCH * 4);
  size_t o_t3n  = alloc((size_t)MSEG * 4);
  size_t o_mean = alloc((size_t)NSUP * CCH * 4);
  size_t o_var  = alloc((size_t)NSUP * CCH * 4);
  size_t o_ssum = alloc((size_t)NSUP * SEG2 * CCH * 4);
  size_t o_t1d  = alloc((size_t)NSUP * SEG2 * CCH * 4);
  size_t o_t1dn = alloc((size_t)NSUP * SEG2 * 4);
  size_t o_cnt  = alloc((size_t)NSUP * SEG2 * 4);
  size_t o_base = alloc((size_t)NSUP * SEG2 * 4);
  size_t o_cur  = alloc((size_t)NSUP * SEG2 * 4);
  size_t o_ord  = alloc((size_t)NSUP * NFEAT * 4);
  size_t o_wib  = alloc((size_t)3 * CCH * CCH * 2);
  size_t o_wob  = alloc((size_t)CCH * CCH * 2);
  size_t o_wfb  = alloc((size_t)4 * CCH * CCH * 2);
  size_t o_wpb  = alloc((size_t)CCH * 4 * CCH * 2);
  size_t o_wa1b = alloc((size_t)AAD * CCH * 2);
  size_t o_wa2b = alloc((size_t)CCH * 64 * 2);                  // wa2 padded to ld 64
  size_t o_watb = alloc((size_t)NSUP * CCH * CCH * 2);
  size_t o_bib  = alloc((size_t)3 * CCH * 4);
  size_t o_bfb  = alloc((size_t)4 * CCH * 4);
  size_t o_bab  = alloc((size_t)NSUP * CCH * 4);

  bf16*  qkv_bf = (bf16*)(wsb + o_qkv);
  bf16*  Vt     = (bf16*)(wsb + o_Vt);
  bf16*  h_bf   = (bf16*)(wsb + o_hbf);
  bf16*  o_bf   = (bf16*)(wsb + o_obf);
  float* x1     = (float*)(wsb + o_x1);
  float* x2     = (float*)(wsb + o_x2);
  float* ffn    = (float*)(wsb + o_ffn);
  bf16*  t_bf   = (bf16*)(wsb + o_tbf);
  bf16*  fx     = (bf16*)(wsb + o_fx);
  float* s3     = (float*)(wsb + o_s3);
  float* t3     = (float*)(wsb + o_t3);
  float* t3n    = (float*)(wsb + o_t3n);
  float* meanb  = (float*)(wsb + o_mean);
  float* varb   = (float*)(wsb + o_var);
  float* ssum   = (float*)(wsb + o_ssum);
  float* t1d    = (float*)(wsb + o_t1d);
  float* t1dn   = (float*)(wsb + o_t1dn);
  int*   cntb   = (int*)(wsb + o_cnt);
  int*   baseb  = (int*)(wsb + o_base);
  int*   curb   = (int*)(wsb + o_cur);
  int*   ordb   = (int*)(wsb + o_ord);
  bf16*  w_in_b = (bf16*)(wsb + o_wib);
  bf16*  w_out_b= (bf16*)(wsb + o_wob);
  bf16*  w_fc_b = (bf16*)(wsb + o_wfb);
  bf16*  w_pj_b = (bf16*)(wsb + o_wpb);
  bf16*  wa1_b  = (bf16*)(wsb + o_wa1b);
  bf16*  wa2_b  = (bf16*)(wsb + o_wa2b);
  bf16*  wat_b  = (bf16*)(wsb + o_watb);
  float* b_in_f = (float*)(wsb + o_bib);
  float* b_fc_f = (float*)(wsb + o_bfb);
  float* b_at_f = (float*)(wsb + o_bab);
  bf16*  fc_bf  = (bf16*)(wsb + o_qkv);  // qkv+Vt dead after attention
  bf16*  ffn_bf = (bf16*)(wsb + o_obf);  // o_bf dead after out-proj

  // ---- weight prep (2 launches): scale/convert table + bias-fold table ----
  prep_kernel<<<dim3((4 * CCH * CCH / 4 + 255) / 256, 12), 256, 0, stream>>>(
      w_in, ln1_g, w_in_b, w_fc, ln2_g, w_fc_b, w_attn1, gn3, wat_b,
      w_out, w_out_b, w_proj, w_pj_b, wa1, wa1_b, wa2, wa2_b);
  fold_kernel<<<dim3(4 * CCH, 8), 64, 0, stream>>>(
      w_in, b_in, ln1_b, b_in_f, w_fc, b_fc, ln2_b, b_fc_f,
      w_attn1, b_attn1, bn3, b_at_f);
  hipMemsetAsync(t_bf, 0, (size_t)NTOK * 64 * 2, stream);  // zero K-pad cols
  // counting sort of flat_grid_index (static per call)
  hist0_kernel<<<(NSUP * SEG2 + 255) / 256, 256, 0, stream>>>(cntb);
  hist_kernel<<<(NSUP * NFEAT + 255) / 256, 256, 0, stream>>>(fgi, cntb);
  scan_kernel<<<NSUP, 256, 0, stream>>>(cntb, baseb, curb);
  place_kernel<<<(NSUP * NFEAT + 255) / 256, 256, 0, stream>>>(fgi, curb, ordb);

  // 1) plain norm(x) -> h_bf   (gamma folded into w_in)
  norm_kernel<<<(NTOK + 3) / 4, 256, 0, stream>>>(x_in, h_bf, 0, NTOK);
  // 2) qkv = norm(x) @ w_in'^T + b_in'
  mgemm_kernel<2, 2><<<dim3(18, 65, 1), 256, 0, stream>>>(
      h_bf, CCH, 0, w_in_b, CCH, 0, nullptr, 0, 0, qkv_bf, 3 * CCH, 0,
      NTOK, 3 * CCH, CCH, b_in_f, 0, 0, 1.0f, nullptr, 0, nullptr, 0, 0, nullptr, 0);
  // 3) V transpose + flash attention
  vtrans_kernel<<<dim3(SEQP / 64, NB * NHEAD), 256, 0, stream>>>(qkv_bf, Vt);
  flash_kernel<<<dim3(SEQP / 64, NB * NHEAD), 256, 0, stream>>>(qkv_bf, Vt, o_bf);
  // 4) x1 = x + o @ w_out^T + b_out
  mgemm_kernel<2, 2><<<dim3(6, 65, 1), 256, 0, stream>>>(
      o_bf, CCH, 0, w_out_b, CCH, 0, x1, CCH, 0, nullptr, 0, 0,
      NTOK, CCH, CCH, b_out, 0, 0, 1.0f, nullptr, 0, x_in, CCH, 0, nullptr, 0);
  // 5) plain norm(x1) -> h_bf
  norm_kernel<<<(NTOK + 3) / 4, 256, 0, stream>>>(x1, h_bf, 0, NTOK);
  // 6) fc = quick_gelu(norm @ w_fc'^T + b_fc')
  mgemm_kernel<2, 2><<<dim3(24, 65, 1), 256, 0, stream>>>(
      h_bf, CCH, 0, w_fc_b, CCH, 0, nullptr, 0, 0, fc_bf, 4 * CCH, 0,
      NTOK, 4 * CCH, CCH, b_fc_f, 0, 1, 1.0f, nullptr, 0, nullptr, 0, 0, nullptr, 0);
  // 7) x_ffn = fc @ w_proj^T + b_proj
  mgemm_kernel<2, 2><<<dim3(6, 65, 1), 256, 0, stream>>>(
      fc_bf, 4 * CCH, 0, w_pj_b, 4 * CCH, 0, ffn, CCH, 0, ffn_bf, CCH, 0,
      NTOK, CCH, 4 * CCH, b_proj, 0, 0, 1.0f, nullptr, 0, nullptr, 0, 0, nullptr, 0);
  // 8) t = quick_gelu(x_ffn @ wa1^T + ba1)   (ld 64, pad cols pre-zeroed)
  mgemm_kernel<2, 2><<<dim3(1, 65, 1), 256, 0, stream>>>(
      ffn_bf, CCH, 0, wa1_b, CCH, 0, nullptr, 0, 0, t_bf, 64, 0,
      NTOK, AAD, CCH, ba1, 0, 1, 1.0f, nullptr, 0, nullptr, 0, 0, nullptr, 0);
  // 9) x2 = x1 + x_ffn + 0.5*(t @ wa2^T + ba2)   (K padded 48->64)
  mgemm_kernel<2, 2><<<dim3(6, 65, 1), 256, 0, stream>>>(
      t_bf, 64, 0, wa2_b, 64, 0, x2, CCH, 0, nullptr, 0, 0,
      NTOK, CCH, 64, ba2, 0, 0, 0.5f, nullptr, 0, x1, CCH, 0, ffn, CCH);
  // 10) cluster pooling -> BN+gelu table t3
  seg1_kernel<<<MSEG, 128, 0, stream>>>(x2, sorted_idx, seg_id, s3);
  bnstats_kernel<<<dim3(CCH, 1), 256, 0, stream>>>(s3, 0, MSEG, meanb, varb, 0);
  bnapply_kernel<<<dim3(MSEG, 1), 128, 0, stream>>>(s3, 0, meanb, varb, 0,
      g3, b3, 0, t3, 0, t3n, 0);
  // 11) branches: shared plain norm of x2, z-batched GEMM (gamma folded) -> fx
  norm_kernel<<<(NFEAT + 3) / 4, 256, 0, stream>>>(x2, h_bf, 1, NFEAT);
  mgemm_kernel<2, 2><<<dim3(6, 64, NSUP), 256, 0, stream>>>(
      h_bf, CCH, 0, wat_b, CCH, (long long)CCH * CCH,
      nullptr, 0, 0, fx, CCH, (long long)NFEAT * CCH,
      NFEAT, CCH, CCH, b_at_f, CCH, 0, 1.0f, maskp, NFEAT, x2, CCH, 1, nullptr, 0);
  // 12) gather-based segment max+mean, then BN+gelu
  seg2_kernel<<<dim3(SEG2, NSUP), 128, 0, stream>>>(fx, baseb, cntb, ordb, ssum);
  bnstats_kernel<<<dim3(CCH, NSUP), 256, 0, stream>>>(
      ssum, (long long)SEG2 * CCH, SEG2, meanb, varb, CCH);
  bnapply_kernel<<<dim3(SEG2, NSUP), 128, 0, stream>>>(
      ssum, (long long)SEG2 * CCH, meanb, varb, CCH,
      g1d, b1d, CCH, t1d, (long long)SEG2 * CCH, t1dn, SEG2);
  // 13) cosine weighting + output
  final_kernel<<<(NTOK + 3) / 4, 256, 0, stream>>>(
      x2, t3, t3n, t1d, t1dn, cluster, fgi, out);
}

// Round 10
// 540.489 us; speedup vs baseline: 1.5032x; 1.0493x over previous
//
#include <hip/hip_runtime.h>
#include <hip/hip_bf16.h>
#include <float.h>
#include <math.h>

#define NB 8
#define CCH 384
#define NHEAD 6
#define DHEAD 64
#define AAD 48
#define MSEG 1024
#define NSUP 6
#define NTOK 8200
#define NFEAT 8192
#define SEG2 1536
#define SEQ 1025
#define SEQP 1088

typedef __hip_bfloat16 bf16;
typedef __attribute__((ext_vector_type(8))) short short8;
typedef __attribute__((ext_vector_type(4))) float floatx4;

// feat row n (0..8191) -> row index in (B,1025,C) token array, skipping CLS
static __device__ __forceinline__ long long tokrow(int n) {
  return (long long)n + (n >> 10) + 1;
}

template<int NT>
static __device__ __forceinline__ float block_reduce_sum(float v, float* s) {
  #pragma unroll
  for (int off = 32; off > 0; off >>= 1) v += __shfl_down(v, off, 64);
  int lane = threadIdx.x & 63, wid = threadIdx.x >> 6;
  if (lane == 0) s[wid] = v;
  __syncthreads();
  if (threadIdx.x == 0) {
    float t = s[0];
    #pragma unroll
    for (int w = 1; w < NT / 64; w++) t += s[w];
    s[0] = t;
  }
  __syncthreads();
  float r = s[0];
  __syncthreads();
  return r;
}

// async global->LDS 16B copy (width=16 verified on gfx950, learn_hip m97)
static __device__ __forceinline__ void async_copy16(void* lds, const void* g) {
  __builtin_amdgcn_global_load_lds(
      (const __attribute__((address_space(1))) unsigned int*)g,
      (__attribute__((address_space(3))) unsigned int*)lds, 16, 0, 0);
}

// ---------------------------------------------------------------------------
// MFMA bf16 GEMM (R9-proven):  C[m,n] = sum_k A[m,k] * Bt[n,k]  (Bt: N x K)
// Wave tile 64x32 (acc = 32 VGPR), block tile 128x64 at <2,2>. BK=64,
// single 24KB LDS. Async global_load_lds staging, XOR granule swizzle.
// ---------------------------------------------------------------------------
template<int WM, int WN>
__global__ __launch_bounds__(256) void mgemm_kernel(
    const bf16* __restrict__ A, int lda, long long sAh,
    const bf16* __restrict__ B, int ldb, long long sBh,
    float* __restrict__ outF, int ldcF, long long sCFh,
    bf16* __restrict__ outB, int ldcB, long long sCBh,
    int M, int N, int K,
    const float* __restrict__ bias, long long sBias, int act, float scale,
    const float* __restrict__ rowmask, long long sMask,
    const float* __restrict__ res1, int ldr1, int res1skip,
    const float* __restrict__ res2, int ldr2)
{
  constexpr int BM = WM * 64, BN = WN * 32;
  __shared__ uint4 Asg[BM * 8];
  __shared__ uint4 Bsg[BN * 8];
  const int z = blockIdx.z;
  const bf16* Ap = A + (long long)z * sAh;
  const bf16* Bp = B + (long long)z * sBh;
  const int tid = threadIdx.x;
  const int m0 = blockIdx.y * BM, n0 = blockIdx.x * BN;
  const int lane = tid & 63, wid = tid >> 6;
  const int wm = (wid % WM) * 64, wn = (wid / WM) * 32;
  const int q = lane >> 4, ln = lane & 15;
  const uint4 zero4 = make_uint4(0, 0, 0, 0);

  const bool fastK = ((K & 63) == 0);
  const bool fastA = fastK && (m0 + BM <= M);
  const bool fastB = fastK && (n0 + BN <= N);

  floatx4 acc[4][2];
  #pragma unroll
  for (int i = 0; i < 4; i++)
    #pragma unroll
    for (int j = 0; j < 2; j++) acc[i][j] = (floatx4){0.f, 0.f, 0.f, 0.f};

  const int nk = (K + 63) >> 6;
  for (int t = 0; t < nk; t++) {
    const int k0 = t * 64;
    __syncthreads();
    if (fastA) {
      #pragma unroll
      for (int p = 0; p < 2 * WM; p++) {
        int idx = p * 256 + tid;
        int row = idx >> 3, g = idx & 7;
        int gs = g ^ (row & 7);
        async_copy16(&Asg[p * 256 + wid * 64],
                     Ap + (long long)(m0 + row) * lda + k0 + gs * 8);
      }
    } else {
      #pragma unroll
      for (int p = 0; p < 2 * WM; p++) {
        int idx = p * 256 + tid;
        int row = idx >> 3, g = idx & 7;
        int gs = g ^ (row & 7);
        int gm = m0 + row, gk = k0 + gs * 8;
        uint4 v = zero4;
        if (gm < M && gk < K)
          v = *reinterpret_cast<const uint4*>(Ap + (long long)gm * lda + gk);
        Asg[idx] = v;
      }
    }
    if (fastB) {
      #pragma unroll
      for (int p = 0; p < WN; p++) {
        int idx = p * 256 + tid;
        int row = idx >> 3, g = idx & 7;
        int gs = g ^ (row & 7);
        async_copy16(&Bsg[p * 256 + wid * 64],
                     Bp + (long long)(n0 + row) * ldb + k0 + gs * 8);
      }
    } else {
      #pragma unroll
      for (int p = 0; p < WN; p++) {
        int idx = p * 256 + tid;
        int row = idx >> 3, g = idx & 7;
        int gs = g ^ (row & 7);
        int gn = n0 + row, gk = k0 + gs * 8;
        uint4 v = zero4;
        if (gn < N && gk < K)
          v = *reinterpret_cast<const uint4*>(Bp + (long long)gn * ldb + gk);
        Bsg[idx] = v;
      }
    }
    asm volatile("s_waitcnt vmcnt(0)" ::: "memory");
    __syncthreads();
    #pragma unroll
    for (int ks = 0; ks < 2; ks++) {
      short8 af[4], bfr[2];
      #pragma unroll
      for (int i = 0; i < 4; i++) {
        int row = wm + i * 16 + ln;
        af[i] = *reinterpret_cast<const short8*>(
            &Asg[row * 8 + ((ks * 4 + q) ^ (ln & 7))]);
      }
      #pragma unroll
      for (int j = 0; j < 2; j++) {
        int row = wn + j * 16 + ln;
        bfr[j] = *reinterpret_cast<const short8*>(
            &Bsg[row * 8 + ((ks * 4 + q) ^ (ln & 7))]);
      }
      #pragma unroll
      for (int i = 0; i < 4; i++)
        #pragma unroll
        for (int j = 0; j < 2; j++)
          acc[i][j] = __builtin_amdgcn_mfma_f32_16x16x32_bf16(af[i], bfr[j], acc[i][j], 0, 0, 0);
    }
  }

  const float* biasz = bias ? bias + z * sBias : nullptr;
  const float* rmz = rowmask ? rowmask + z * sMask : nullptr;
  float* cF = outF ? outF + (long long)z * sCFh : nullptr;
  bf16*  cB = outB ? outB + (long long)z * sCBh : nullptr;
  #pragma unroll
  for (int i = 0; i < 4; i++) {
    #pragma unroll
    for (int r = 0; r < 4; r++) {
      int gm = m0 + wm + i * 16 + q * 4 + r;
      if (gm >= M) continue;
      float rm = rmz ? rmz[gm] : 1.0f;
      long long r1off = 0;
      if (res1) r1off = (res1skip ? tokrow(gm) : (long long)gm) * ldr1;
      #pragma unroll
      for (int j = 0; j < 2; j++) {
        int gn = n0 + wn + j * 16 + ln;
        if (gn >= N) continue;
        float v = acc[i][j][r];
        if (biasz) v += biasz[gn];
        if (act) v = v / (1.0f + __expf(-1.702f * v));  // quick_gelu
        v *= scale * rm;
        if (res1) v += res1[r1off + gn];
        if (res2) v += res2[(long long)gm * ldr2 + gn];
        if (cF) cF[(long long)gm * ldcF + gn] = v;
        if (cB) cB[(long long)gm * ldcB + gn] = __float2bfloat16(v);
      }
    }
  }
}

// ---------------------------------------------------------------------------
// Unified weight-prep kernel (table over blockIdx.y):
//  y=0: w_in*ln1_g (Q rows scaled by 0.125)  y=1: w_fc*ln2_g
//  y=2..7: w_attn1[z]*gn3[z]  y=8: w_out  y=9: w_proj  y=10: wa1
//  y=11: wa2 padded to ld 64
// ---------------------------------------------------------------------------
__global__ void prep_kernel(
    const float* __restrict__ w_in, const float* __restrict__ ln1_g, bf16* __restrict__ w_in_b,
    const float* __restrict__ w_fc, const float* __restrict__ ln2_g, bf16* __restrict__ w_fc_b,
    const float* __restrict__ w_attn1, const float* __restrict__ gn3, bf16* __restrict__ wat_b,
    const float* __restrict__ w_out, bf16* __restrict__ w_out_b,
    const float* __restrict__ w_proj, bf16* __restrict__ w_pj_b,
    const float* __restrict__ wa1, bf16* __restrict__ wa1_b,
    const float* __restrict__ wa2, bf16* __restrict__ wa2_b)
{
  int y = blockIdx.y;
  int i = (blockIdx.x * 256 + threadIdx.x) * 4;
  if (y == 11) {
    if (i >= CCH * 64) return;
    int r = i >> 6, c = i & 63;
    #pragma unroll
    for (int e = 0; e < 4; e++)
      wa2_b[i + e] = __float2bfloat16((c + e) < AAD ? wa2[r * AAD + c + e] : 0.f);
    return;
  }
  const float* s; bf16* d; const float* g = nullptr; int n;
  if (y == 0)      { s = w_in;  d = w_in_b;  g = ln1_g; n = 3 * CCH * CCH; }
  else if (y == 1) { s = w_fc;  d = w_fc_b;  g = ln2_g; n = 4 * CCH * CCH; }
  else if (y <= 7) { int z = y - 2;
                     s = w_attn1 + (long long)z * CCH * CCH;
                     d = wat_b   + (long long)z * CCH * CCH;
                     g = gn3 + z * CCH; n = CCH * CCH; }
  else if (y == 8) { s = w_out;  d = w_out_b; n = CCH * CCH; }
  else if (y == 9) { s = w_proj; d = w_pj_b;  n = 4 * CCH * CCH; }
  else             { s = wa1;   d = wa1_b;   n = AAD * CCH; }
  if (i >= n) return;
  float4 v = *reinterpret_cast<const float4*>(s + i);
  if (g) {
    int k = i % CCH;
    v.x *= g[k]; v.y *= g[k + 1]; v.z *= g[k + 2]; v.w *= g[k + 3];
  }
  if (y == 0 && (i / CCH) < CCH) {       // Q rows: fold 1/8 attention scale
    v.x *= 0.125f; v.y *= 0.125f; v.z *= 0.125f; v.w *= 0.125f;
  }
  d[i]     = __float2bfloat16(v.x);
  d[i + 1] = __float2bfloat16(v.y);
  d[i + 2] = __float2bfloat16(v.z);
  d[i + 3] = __float2bfloat16(v.w);
}

// Unified bias-fold: out[n] = b[n] + sum_k beta[k] * W[n][k]; one wave/row.
__global__ __launch_bounds__(64) void fold_kernel(
    const float* __restrict__ w_in, const float* __restrict__ b_in,
    const float* __restrict__ ln1_b, float* __restrict__ b_in_f,
    const float* __restrict__ w_fc, const float* __restrict__ b_fc,
    const float* __restrict__ ln2_b, float* __restrict__ b_fc_f,
    const float* __restrict__ w_attn1, const float* __restrict__ b_attn1,
    const float* __restrict__ bn3, float* __restrict__ b_at_f)
{
  int y = blockIdx.y, n = blockIdx.x;
  const float* W; const float* b; const float* beta; float* o; int rows;
  if (y == 0)      { W = w_in; b = b_in; beta = ln1_b; o = b_in_f; rows = 3 * CCH; }
  else if (y == 1) { W = w_fc; b = b_fc; beta = ln2_b; o = b_fc_f; rows = 4 * CCH; }
  else             { int z = y - 2;
                     W = w_attn1 + (long long)z * CCH * CCH; b = b_attn1 + z * CCH;
                     beta = bn3 + z * CCH; o = b_at_f + z * CCH; rows = CCH; }
  if (n >= rows) return;
  const float* Wr = W + (long long)n * CCH;
  float s = 0.f;
  for (int k = threadIdx.x; k < CCH; k += 64) s += Wr[k] * beta[k];
  #pragma unroll
  for (int off = 32; off > 0; off >>= 1) s += __shfl_down(s, off, 64);
  if (threadIdx.x == 0) {
    float r = b[n] + s;
    if (y == 0 && n < CCH) r *= 0.125f;   // Q bias: fold 1/8 attention scale
    o[n] = r;
  }
}

// plain LayerNorm (no affine), one WAVE per row, shuffle-only
__global__ __launch_bounds__(256) void norm_kernel(
    const float* __restrict__ in, bf16* __restrict__ out, int skipcls, int nrows)
{
  int r = blockIdx.x * 4 + (threadIdx.x >> 6);
  if (r >= nrows) return;
  int lane = threadIdx.x & 63;
  long long ir = skipcls ? tokrow(r) : (long long)r;
  const float* x = in + ir * CCH;
  float v[6];
  float s = 0.f, s2 = 0.f;
  #pragma unroll
  for (int k = 0; k < 6; k++) {
    v[k] = x[lane + k * 64];
    s += v[k]; s2 += v[k] * v[k];
  }
  #pragma unroll
  for (int off = 32; off > 0; off >>= 1) {
    s  += __shfl_xor(s, off, 64);
    s2 += __shfl_xor(s2, off, 64);
  }
  float m = s * (1.0f / CCH);
  float var = s2 * (1.0f / CCH) - m * m;
  float rstd = rsqrtf(var + 1e-5f);
  bf16* o = out + (long long)r * CCH;
  #pragma unroll
  for (int k = 0; k < 6; k++)
    o[lane + k * 64] = __float2bfloat16((v[k] - m) * rstd);
}

// V (within qkv, [s][2C + h*64+d]) -> Vt [bh][d][s padded to 1088], zero tail
__global__ __launch_bounds__(256) void vtrans_kernel(
    const bf16* __restrict__ qkv, bf16* __restrict__ Vt)
{
  __shared__ bf16 tile[64][68];
  int bh = blockIdx.y;
  int b = bh / NHEAD, h = bh % NHEAD;
  int s0 = blockIdx.x * 64;
  int dq = (threadIdx.x & 15) * 4;
  int sl = threadIdx.x >> 4;
  #pragma unroll
  for (int p = 0; p < 4; p++) {
    int sloc = sl + p * 16;
    int s = s0 + sloc;
    uint2 v = make_uint2(0, 0);
    if (s < SEQ)
      v = *reinterpret_cast<const uint2*>(
            qkv + ((long long)(b * SEQ + s)) * (3 * CCH) + 2 * CCH + h * DHEAD + dq);
    *reinterpret_cast<uint2*>(&tile[sloc][dq]) = v;
  }
  __syncthreads();
  #pragma unroll
  for (int p = 0; p < 4; p++) {
    int dloc = sl + p * 16;
    int s4 = dq;
    bf16 t0 = tile[s4 + 0][dloc], t1 = tile[s4 + 1][dloc];
    bf16 t2 = tile[s4 + 2][dloc], t3 = tile[s4 + 3][dloc];
    bf16* dst = Vt + ((long long)bh * DHEAD + dloc) * SEQP + s0 + s4;
    dst[0] = t0; dst[1] = t1; dst[2] = t2; dst[3] = t3;
  }
}

// ---------------------------------------------------------------------------
// Flash attention v2: grid (17 q-tiles, 48 bh). 4 waves x 16 q-rows.
// No online max (logits bounded; softmax shift-invariant -> exact).
// Row sums via ones-column MFMA (osum). XOR-swizzled 8-granule LDS layout
// for Kt/Vtt/Pt -> conflict-free b128 reads, 2-way-max writes. 24KB LDS.
// Q is pre-scaled by 0.125 (folded into w_in/b_in during prep).
// ---------------------------------------------------------------------------
__global__ __launch_bounds__(256) void flash_kernel(
    const bf16* __restrict__ qkv, const bf16* __restrict__ Vt,
    bf16* __restrict__ O)
{
  __shared__ uint4 Kt[64 * 8];
  __shared__ uint4 Vtt[64 * 8];
  __shared__ uint4 Pt[64 * 8];
  const int bh = blockIdx.y;
  const int b = bh / NHEAD, h = bh % NHEAD;
  const int q0 = blockIdx.x * 64;
  const int tid = threadIdx.x;
  const int lane = tid & 63, w = tid >> 6;
  const int q = lane >> 4, ln = lane & 15;
  const uint4 zero4 = make_uint4(0, 0, 0, 0);

  short8 aq[2];
  {
    int qrow = q0 + w * 16 + ln;
    #pragma unroll
    for (int ks = 0; ks < 2; ks++) {
      if (qrow < SEQ)
        aq[ks] = *reinterpret_cast<const short8*>(
            qkv + ((long long)(b * SEQ + qrow)) * (3 * CCH) + h * DHEAD + ks * 32 + q * 8);
      else
        aq[ks] = (short8){0, 0, 0, 0, 0, 0, 0, 0};
    }
  }
  const short ob = (short)0x3F80;  // bf16 1.0
  const short8 ones = {ob, ob, ob, ob, ob, ob, ob, ob};

  floatx4 oacc[4], osum;
  #pragma unroll
  for (int j = 0; j < 4; j++) oacc[j] = (floatx4){0.f, 0.f, 0.f, 0.f};
  osum = (floatx4){0.f, 0.f, 0.f, 0.f};

  for (int kt = 0; kt < SEQP / 64; kt++) {
    __syncthreads();
    #pragma unroll
    for (int p = 0; p < 2; p++) {
      int g = p * 256 + tid;
      int row = g >> 3, k8 = g & 7;
      int gs = k8 ^ (row & 7);
      int sg = kt * 64 + row;
      uint4 kv = zero4;
      if (sg < SEQ)
        kv = *reinterpret_cast<const uint4*>(
              qkv + ((long long)(b * SEQ + sg)) * (3 * CCH) + CCH + h * DHEAD + gs * 8);
      Kt[row * 8 + k8] = kv;
      Vtt[row * 8 + k8] = *reinterpret_cast<const uint4*>(
              Vt + ((long long)bh * DHEAD + row) * SEQP + kt * 64 + gs * 8);
    }
    __syncthreads();

    floatx4 sa[4];
    #pragma unroll
    for (int j = 0; j < 4; j++) sa[j] = (floatx4){0.f, 0.f, 0.f, 0.f};
    #pragma unroll
    for (int ks = 0; ks < 2; ks++) {
      #pragma unroll
      for (int j = 0; j < 4; j++) {
        short8 kb = *reinterpret_cast<const short8*>(
            &Kt[(j * 16 + ln) * 8 + ((ks * 4 + q) ^ (ln & 7))]);
        sa[j] = __builtin_amdgcn_mfma_f32_16x16x32_bf16(aq[ks], kb, sa[j], 0, 0, 0);
      }
    }

    // P = exp(S) (no max shift; logits bounded), zero padded keys on last tile
    bf16* pbase = reinterpret_cast<bf16*>(Pt);
    const bool lastT = (kt == SEQP / 64 - 1);
    #pragma unroll
    for (int r = 0; r < 4; r++) {
      int row = w * 16 + q * 4 + r;
      bf16* prow = pbase + row * 64;
      #pragma unroll
      for (int j = 0; j < 4; j++) {
        float pv = __expf(sa[j][r]);
        int col = j * 16 + ln;
        if (lastT && (kt * 64 + col >= SEQ)) pv = 0.f;
        int slot = (col >> 3) ^ (row & 7);
        prow[slot * 8 + (col & 7)] = __float2bfloat16(pv);
      }
    }
    // PV (+ ones column -> row sums); own wave's rows only, no barrier
    #pragma unroll
    for (int ks = 0; ks < 2; ks++) {
      short8 ap = *reinterpret_cast<const short8*>(
          pbase + (w * 16 + ln) * 64 + ((ks * 4 + q) ^ (ln & 7)) * 8);
      #pragma unroll
      for (int j = 0; j < 4; j++) {
        short8 vb = *reinterpret_cast<const short8*>(
            &Vtt[(j * 16 + ln) * 8 + ((ks * 4 + q) ^ (ln & 7))]);
        oacc[j] = __builtin_amdgcn_mfma_f32_16x16x32_bf16(ap, vb, oacc[j], 0, 0, 0);
      }
      osum = __builtin_amdgcn_mfma_f32_16x16x32_bf16(ap, ones, osum, 0, 0, 0);
    }
  }

  #pragma unroll
  for (int r = 0; r < 4; r++) {
    int qrow = q0 + w * 16 + q * 4 + r;
    if (qrow >= SEQ) continue;
    float inv = 1.0f / osum[r];
    bf16* orow = O + ((long long)(b * SEQ + qrow)) * CCH + h * DHEAD;
    #pragma unroll
    for (int j = 0; j < 4; j++)
      orow[j * 16 + ln] = __float2bfloat16(oacc[j][r] * inv);
  }
}

// sorted-segment max+mean over cluster ids; one block per segment
__global__ __launch_bounds__(128) void seg1_kernel(
    const float* __restrict__ x2, const int* __restrict__ sorted_idx,
    const int* __restrict__ seg_id, float* __restrict__ s3)
{
  int s = blockIdx.x;
  int lo = 0, hi = NFEAT;
  while (lo < hi) { int mid = (lo + hi) >> 1; if (seg_id[mid] < s) lo = mid + 1; else hi = mid; }
  int start = lo;
  hi = NFEAT;
  while (lo < hi) { int mid = (lo + hi) >> 1; if (seg_id[mid] < s + 1) lo = mid + 1; else hi = mid; }
  int end = lo;
  int cnt = end - start;
  for (int c = threadIdx.x; c < CCH; c += 128) {
    float sum = 0.f, mx = -FLT_MAX;
    for (int r = start; r < end; r++) {
      int n = sorted_idx[r];
      float v = x2[tokrow(n) * CCH + c];
      sum += v; mx = fmaxf(mx, v);
    }
    float u = (cnt > 0 ? mx : 0.f) + sum / fmaxf((float)cnt, 1.0f);
    s3[(long long)s * CCH + c] = u;
  }
}

// counting sort over flat_grid_index: hist -> scan -> place
__global__ void hist0_kernel(int* __restrict__ cnt)
{
  int idx = blockIdx.x * 256 + threadIdx.x;
  if (idx < NSUP * SEG2) cnt[idx] = 0;
}
__global__ void hist_kernel(const int* __restrict__ fgi, int* __restrict__ cnt)
{
  int idx = blockIdx.x * 256 + threadIdx.x;
  if (idx >= NSUP * NFEAT) return;
  int z = idx >> 13;
  atomicAdd(&cnt[z * SEG2 + fgi[idx]], 1);
}
__global__ __launch_bounds__(256) void scan_kernel(
    const int* __restrict__ cnt, int* __restrict__ base, int* __restrict__ cur)
{
  int z = blockIdx.x, t = threadIdx.x;
  __shared__ int sdata[256];
  const int* c = cnt + z * SEG2;
  int loc[6]; int s = 0;
  #pragma unroll
  for (int e = 0; e < 6; e++) { loc[e] = s; s += c[t * 6 + e]; }
  sdata[t] = s;
  __syncthreads();
  for (int off = 1; off < 256; off <<= 1) {
    int v = (t >= off) ? sdata[t - off] : 0;
    __syncthreads();
    sdata[t] += v;
    __syncthreads();
  }
  int pre = (t > 0) ? sdata[t - 1] : 0;
  #pragma unroll
  for (int e = 0; e < 6; e++) {
    int b = pre + loc[e];
    base[z * SEG2 + t * 6 + e] = b;
    cur[z * SEG2 + t * 6 + e] = b;
  }
}
__global__ void place_kernel(const int* __restrict__ fgi, int* __restrict__ cur,
                             int* __restrict__ order)
{
  int idx = blockIdx.x * 256 + threadIdx.x;
  if (idx >= NSUP * NFEAT) return;
  int z = idx >> 13, n = idx & (NFEAT - 1);
  int s = fgi[idx];
  int pos = atomicAdd(&cur[z * SEG2 + s], 1);
  order[z * NFEAT + pos] = n;
}

// gather-based segment max+mean from fx (bf16) -> u[z][s][c]
__global__ __launch_bounds__(128) void seg2_kernel(
    const bf16* __restrict__ fx, const int* __restrict__ base,
    const int* __restrict__ cnt, const int* __restrict__ order,
    float* __restrict__ u)
{
  int s = blockIdx.x, z = blockIdx.y;
  int st = base[z * SEG2 + s], c = cnt[z * SEG2 + s];
  const int* ord = order + z * NFEAT;
  const bf16* fz = fx + (long long)z * NFEAT * CCH;
  for (int ch = threadIdx.x; ch < CCH; ch += 128) {
    float sum = 0.f, mx = -FLT_MAX;
    for (int r = 0; r < c; r++) {
      float v = __bfloat162float(fz[(long long)ord[st + r] * CCH + ch]);
      sum += v; mx = fmaxf(mx, v);
    }
    u[((long long)z * SEG2 + s) * CCH + ch] = (c > 0 ? mx : 0.f) + sum / fmaxf((float)c, 1.0f);
  }
}

// per-channel batchnorm stats; z-batched
__global__ __launch_bounds__(256) void bnstats_kernel(
    const float* __restrict__ u, long long sU, int rows,
    float* __restrict__ mean, float* __restrict__ var, long long sMV)
{
  int c = blockIdx.x, z = blockIdx.y;
  u += z * sU; mean += z * sMV; var += z * sMV;
  float s = 0.f, s2 = 0.f;
  for (int r = threadIdx.x; r < rows; r += 256) {
    float v = u[(long long)r * CCH + c];
    s += v; s2 += v * v;
  }
  __shared__ float sb[4];
  s  = block_reduce_sum<256>(s, sb);
  s2 = block_reduce_sum<256>(s2, sb);
  if (threadIdx.x == 0) {
    float m = s / rows;
    mean[c] = m;
    var[c] = s2 / rows - m * m;
  }
}

// BN + exact gelu, result + row L2 norm; z-batched
__global__ __launch_bounds__(128) void bnapply_kernel(
    const float* __restrict__ u, long long sU,
    const float* __restrict__ mean, const float* __restrict__ var, long long sMV,
    const float* __restrict__ g, const float* __restrict__ b, long long sGB,
    float* __restrict__ t, long long sT, float* __restrict__ norms, long long sN)
{
  int r = blockIdx.x, z = blockIdx.y;
  u += z * sU; mean += z * sMV; var += z * sMV; g += z * sGB; b += z * sGB;
  t += z * sT; norms += z * sN;
  float ss = 0.f;
  #pragma unroll
  for (int e = 0; e < 3; e++) {
    int c = threadIdx.x + e * 128;
    float v = u[(long long)r * CCH + c];
    float y = (v - mean[c]) * rsqrtf(var[c] + 1e-5f) * g[c] + b[c];
    float ge = 0.5f * y * (1.0f + erff(y * 0.70710678118654752f));
    t[(long long)r * CCH + c] = ge;
    ss += ge * ge;
  }
  __shared__ float sb[2];
  ss = block_reduce_sum<128>(ss, sb);
  if (threadIdx.x == 0) norms[r] = sqrtf(ss);
}

// cosine-sim weighting + final output; one WAVE per row, shuffle-only
__global__ __launch_bounds__(256) void final_kernel(
    const float* __restrict__ x2, const float* __restrict__ t3,
    const float* __restrict__ t3norm, const float* __restrict__ t1d,
    const float* __restrict__ t1dnorm, const int* __restrict__ cluster,
    const int* __restrict__ fgi, float* __restrict__ out)
{
  int row = blockIdx.x * 4 + (threadIdx.x >> 6);
  if (row >= NTOK) return;
  int lane = threadIdx.x & 63;
  int b = row / SEQ, gg = row - b * SEQ;
  const float* xr = x2 + (long long)row * CCH;
  float* orow = out + (long long)row * CCH;
  float xv[6];
  #pragma unroll
  for (int k = 0; k < 6; k++) xv[k] = xr[lane + k * 64];
  if (gg == 0) {
    #pragma unroll
    for (int k = 0; k < 6; k++) orow[lane + k * 64] = xv[k];
    return;
  }
  int n = b * 1024 + gg - 1;
  int c3 = cluster[n];
  const float* a3 = t3 + (long long)c3 * CCH;
  float a3v[6];
  #pragma unroll
  for (int k = 0; k < 6; k++) a3v[k] = a3[lane + k * 64];
  float nb = fmaxf(t3norm[c3], 1e-8f);
  float w[NSUP];
  const float* rows[NSUP];
  float tot = 0.f;
  #pragma unroll
  for (int i = 0; i < NSUP; i++) {
    int s = fgi[i * NFEAT + n];
    const float* ar = t1d + ((long long)i * SEG2 + s) * CCH;
    rows[i] = ar;
    float d = 0.f;
    #pragma unroll
    for (int k = 0; k < 6; k++) d += ar[lane + k * 64] * a3v[k];
    #pragma unroll
    for (int off = 32; off > 0; off >>= 1) d += __shfl_xor(d, off, 64);
    float na = fmaxf(t1dnorm[i * SEG2 + s], 1e-8f);
    float cosv = d / (na * nb);
    w[i] = (cosv + 1.0f) * 0.5f;
    tot += w[i];
  }
  float inv = 1.0f / tot;
  #pragma unroll
  for (int k = 0; k < 6; k++) {
    float acc = 0.f;
    #pragma unroll
    for (int i = 0; i < NSUP; i++) acc += w[i] * rows[i][lane + k * 64];
    orow[lane + k * 64] = xv[k] + 0.3f * acc * inv;
  }
}

extern "C" void kernel_launch(void* const* d_in, const int* in_sizes, int n_in,
                              void* d_out, int out_size, void* d_ws, size_t ws_size,
                              hipStream_t stream)
{
  const float* x_in   = (const float*)d_in[0];
  const float* maskp  = (const float*)d_in[1];
  const float* ln1_g  = (const float*)d_in[2];
  const float* ln1_b  = (const float*)d_in[3];
  const float* ln2_g  = (const float*)d_in[4];
  const float* ln2_b  = (const float*)d_in[5];
  const float* w_in   = (const float*)d_in[6];
  const float* b_in   = (const float*)d_in[7];
  const float* w_out  = (const float*)d_in[8];
  const float* b_out  = (const float*)d_in[9];
  const float* w_fc   = (const float*)d_in[10];
  const float* b_fc   = (const float*)d_in[11];
  const float* w_proj = (const float*)d_in[12];
  const float* b_proj = (const float*)d_in[13];
  const float* wa1    = (const float*)d_in[14];
  const float* ba1    = (const float*)d_in[15];
  const float* wa2    = (const float*)d_in[16];
  const float* ba2    = (const float*)d_in[17];
  const float* g3     = (const float*)d_in[18];
  const float* b3     = (const float*)d_in[19];
  const float* g1d    = (const float*)d_in[20];
  const float* b1d    = (const float*)d_in[21];
  const float* gn3    = (const float*)d_in[22];
  const float* bn3    = (const float*)d_in[23];
  const float* w_attn1= (const float*)d_in[24];
  const float* b_attn1= (const float*)d_in[25];
  const int* sorted_idx = (const int*)d_in[26];
  const int* seg_id   = (const int*)d_in[27];
  const int* cluster  = (const int*)d_in[28];
  const int* fgi      = (const int*)d_in[29];
  float* out = (float*)d_out;
  char* wsb = (char*)d_ws;

  size_t off = 0;
  auto alloc = [&](size_t bytes) { size_t o = off; off += (bytes + 255) & ~(size_t)255; return o; };
  size_t o_qkv  = alloc((size_t)NTOK * 3 * CCH * 2);            // qkv bf16
  size_t o_Vt   = alloc((size_t)NB * NHEAD * DHEAD * SEQP * 2); // Vt; qkv+Vt reused as fc_bf
  size_t o_hbf  = alloc((size_t)NTOK * CCH * 2);                // norm out bf16 (reused 3x)
  size_t o_obf  = alloc((size_t)NTOK * CCH * 2);                // attn out; later ffn_bf
  size_t o_x1   = alloc((size_t)NTOK * CCH * 4);
  size_t o_x2   = alloc((size_t)NTOK * CCH * 4);
  size_t o_ffn  = alloc((size_t)NTOK * CCH * 4);
  size_t o_tbf  = alloc((size_t)NTOK * 64 * 2);                 // adapter t, ld 64 (padded)
  size_t o_fx   = alloc((size_t)NSUP * NFEAT * CCH * 2);        // branch out bf16
  size_t o_s3   = alloc((size_t)MSEG * CCH * 4);
  size_t o_t3   = alloc((size_t)MSEG * CCH * 4);
  size_t o_t3n  = alloc((size_t)MSEG * 4);
  size_t o_mean = alloc((size_t)NSUP * CCH * 4);
  size_t o_var  = alloc((size_t)NSUP * CCH * 4);
  size_t o_ssum = alloc((size_t)NSUP * SEG2 * CCH * 4);
  size_t o_t1d  = alloc((size_t)NSUP * SEG2 * CCH * 4);
  size_t o_t1dn = alloc((size_t)NSUP * SEG2 * 4);
  size_t o_cnt  = alloc((size_t)NSUP * SEG2 * 4);
  size_t o_base = alloc((size_t)NSUP * SEG2 * 4);
  size_t o_cur  = alloc((size_t)NSUP * SEG2 * 4);
  size_t o_ord  = alloc((size_t)NSUP * NFEAT * 4);
  size_t o_wib  = alloc((size_t)3 * CCH * CCH * 2);
  size_t o_wob  = alloc((size_t)CCH * CCH * 2);
  size_t o_wfb  = alloc((size_t)4 * CCH * CCH * 2);
  size_t o_wpb  = alloc((size_t)CCH * 4 * CCH * 2);
  size_t o_wa1b = alloc((size_t)AAD * CCH * 2);
  size_t o_wa2b = alloc((size_t)CCH * 64 * 2);                  // wa2 padded to ld 64
  size_t o_watb = alloc((size_t)NSUP * CCH * CCH * 2);
  size_t o_bib  = alloc((size_t)3 * CCH * 4);
  size_t o_bfb  = alloc((size_t)4 * CCH * 4);
  size_t o_bab  = alloc((size_t)NSUP * CCH * 4);

  bf16*  qkv_bf = (bf16*)(wsb + o_qkv);
  bf16*  Vt     = (bf16*)(wsb + o_Vt);
  bf16*  h_bf   = (bf16*)(wsb + o_hbf);
  bf16*  o_bf   = (bf16*)(wsb + o_obf);
  float* x1     = (float*)(wsb + o_x1);
  float* x2     = (float*)(wsb + o_x2);
  float* ffn    = (float*)(wsb + o_ffn);
  bf16*  t_bf   = (bf16*)(wsb + o_tbf);
  bf16*  fx     = (bf16*)(wsb + o_fx);
  float* s3     = (float*)(wsb + o_s3);
  float* t3     = (float*)(wsb + o_t3);
  float* t3n    = (float*)(wsb + o_t3n);
  float* meanb  = (float*)(wsb + o_mean);
  float* varb   = (float*)(wsb + o_var);
  float* ssum   = (float*)(wsb + o_ssum);
  float* t1d    = (float*)(wsb + o_t1d);
  float* t1dn   = (float*)(wsb + o_t1dn);
  int*   cntb   = (int*)(wsb + o_cnt);
  int*   baseb  = (int*)(wsb + o_base);
  int*   curb   = (int*)(wsb + o_cur);
  int*   ordb   = (int*)(wsb + o_ord);
  bf16*  w_in_b = (bf16*)(wsb + o_wib);
  bf16*  w_out_b= (bf16*)(wsb + o_wob);
  bf16*  w_fc_b = (bf16*)(wsb + o_wfb);
  bf16*  w_pj_b = (bf16*)(wsb + o_wpb);
  bf16*  wa1_b  = (bf16*)(wsb + o_wa1b);
  bf16*  wa2_b  = (bf16*)(wsb + o_wa2b);
  bf16*  wat_b  = (bf16*)(wsb + o_watb);
  float* b_in_f = (float*)(wsb + o_bib);
  float* b_fc_f = (float*)(wsb + o_bfb);
  float* b_at_f = (float*)(wsb + o_bab);
  bf16*  fc_bf  = (bf16*)(wsb + o_qkv);  // qkv+Vt dead after attention
  bf16*  ffn_bf = (bf16*)(wsb + o_obf);  // o_bf dead after out-proj

  // ---- weight prep (2 launches): scale/convert table + bias-fold table ----
  prep_kernel<<<dim3((4 * CCH * CCH / 4 + 255) / 256, 12), 256, 0, stream>>>(
      w_in, ln1_g, w_in_b, w_fc, ln2_g, w_fc_b, w_attn1, gn3, wat_b,
      w_out, w_out_b, w_proj, w_pj_b, wa1, wa1_b, wa2, wa2_b);
  fold_kernel<<<dim3(4 * CCH, 8), 64, 0, stream>>>(
      w_in, b_in, ln1_b, b_in_f, w_fc, b_fc, ln2_b, b_fc_f,
      w_attn1, b_attn1, bn3, b_at_f);
  hipMemsetAsync(t_bf, 0, (size_t)NTOK * 64 * 2, stream);  // zero K-pad cols
  // counting sort of flat_grid_index (static per call)
  hist0_kernel<<<(NSUP * SEG2 + 255) / 256, 256, 0, stream>>>(cntb);
  hist_kernel<<<(NSUP * NFEAT + 255) / 256, 256, 0, stream>>>(fgi, cntb);
  scan_kernel<<<NSUP, 256, 0, stream>>>(cntb, baseb, curb);
  place_kernel<<<(NSUP * NFEAT + 255) / 256, 256, 0, stream>>>(fgi, curb, ordb);

  // 1) plain norm(x) -> h_bf   (gamma folded into w_in)
  norm_kernel<<<(NTOK + 3) / 4, 256, 0, stream>>>(x_in, h_bf, 0, NTOK);
  // 2) qkv = norm(x) @ w_in'^T + b_in'   (Q pre-scaled by 1/8)
  mgemm_kernel<2, 2><<<dim3(18, 65, 1), 256, 0, stream>>>(
      h_bf, CCH, 0, w_in_b, CCH, 0, nullptr, 0, 0, qkv_bf, 3 * CCH, 0,
      NTOK, 3 * CCH, CCH, b_in_f, 0, 0, 1.0f, nullptr, 0, nullptr, 0, 0, nullptr, 0);
  // 3) V transpose + flash attention
  vtrans_kernel<<<dim3(SEQP / 64, NB * NHEAD), 256, 0, stream>>>(qkv_bf, Vt);
  flash_kernel<<<dim3(SEQP / 64, NB * NHEAD), 256, 0, stream>>>(qkv_bf, Vt, o_bf);
  // 4) x1 = x + o @ w_out^T + b_out
  mgemm_kernel<2, 2><<<dim3(6, 65, 1), 256, 0, stream>>>(
      o_bf, CCH, 0, w_out_b, CCH, 0, x1, CCH, 0, nullptr, 0, 0,
      NTOK, CCH, CCH, b_out, 0, 0, 1.0f, nullptr, 0, x_in, CCH, 0, nullptr, 0);
  // 5) plain norm(x1) -> h_bf
  norm_kernel<<<(NTOK + 3) / 4, 256, 0, stream>>>(x1, h_bf, 0, NTOK);
  // 6) fc = quick_gelu(norm @ w_fc'^T + b_fc')
  mgemm_kernel<2, 2><<<dim3(24, 65, 1), 256, 0, stream>>>(
      h_bf, CCH, 0, w_fc_b, CCH, 0, nullptr, 0, 0, fc_bf, 4 * CCH, 0,
      NTOK, 4 * CCH, CCH, b_fc_f, 0, 1, 1.0f, nullptr, 0, nullptr, 0, 0, nullptr, 0);
  // 7) x_ffn = fc @ w_proj^T + b_proj
  mgemm_kernel<2, 2><<<dim3(6, 65, 1), 256, 0, stream>>>(
      fc_bf, 4 * CCH, 0, w_pj_b, 4 * CCH, 0, ffn, CCH, 0, ffn_bf, CCH, 0,
      NTOK, CCH, 4 * CCH, b_proj, 0, 0, 1.0f, nullptr, 0, nullptr, 0, 0, nullptr, 0);
  // 8) t = quick_gelu(x_ffn @ wa1^T + ba1)   (ld 64, pad cols pre-zeroed)
  mgemm_kernel<2, 2><<<dim3(1, 65, 1), 256, 0, stream>>>(
      ffn_bf, CCH, 0, wa1_b, CCH, 0, nullptr, 0, 0, t_bf, 64, 0,
      NTOK, AAD, CCH, ba1, 0, 1, 1.0f, nullptr, 0, nullptr, 0, 0, nullptr, 0);
  // 9) x2 = x1 + x_ffn + 0.5*(t @ wa2^T + ba2)   (K padded 48->64)
  mgemm_kernel<2, 2><<<dim3(6, 65, 1), 256, 0, stream>>>(
      t_bf, 64, 0, wa2_b, 64, 0, x2, CCH, 0, nullptr, 0, 0,
      NTOK, CCH, 64, ba2, 0, 0, 0.5f, nullptr, 0, x1, CCH, 0, ffn, CCH);
  // 10) cluster pooling -> BN+gelu table t3
  seg1_kernel<<<MSEG, 128, 0, stream>>>(x2, sorted_idx, seg_id, s3);
  bnstats_kernel<<<dim3(CCH, 1), 256, 0, stream>>>(s3, 0, MSEG, meanb, varb, 0);
  bnapply_kernel<<<dim3(MSEG, 1), 128, 0, stream>>>(s3, 0, meanb, varb, 0,
      g3, b3, 0, t3, 0, t3n, 0);
  // 11) branches: shared plain norm of x2, z-batched GEMM (gamma folded) -> fx
  norm_kernel<<<(NFEAT + 3) / 4, 256, 0, stream>>>(x2, h_bf, 1, NFEAT);
  mgemm_kernel<2, 2><<<dim3(6, 64, NSUP), 256, 0, stream>>>(
      h_bf, CCH, 0, wat_b, CCH, (long long)CCH * CCH,
      nullptr, 0, 0, fx, CCH, (long long)NFEAT * CCH,
      NFEAT, CCH, CCH, b_at_f, CCH, 0, 1.0f, maskp, NFEAT, x2, CCH, 1, nullptr, 0);
  // 12) gather-based segment max+mean, then BN+gelu
  seg2_kernel<<<dim3(SEG2, NSUP), 128, 0, stream>>>(fx, baseb, cntb, ordb, ssum);
  bnstats_kernel<<<dim3(CCH, NSUP), 256, 0, stream>>>(
      ssum, (long long)SEG2 * CCH, SEG2, meanb, varb, CCH);
  bnapply_kernel<<<dim3(SEG2, NSUP), 128, 0, stream>>>(
      ssum, (long long)SEG2 * CCH, meanb, varb, CCH,
      g1d, b1d, CCH, t1d, (long long)SEG2 * CCH, t1dn, SEG2);
  // 13) cosine weighting + output
  final_kernel<<<(NTOK + 3) / 4, 256, 0, stream>>>(
      x2, t3, t3n, t1d, t1dn, cluster, fgi, out);
}